// Round 6
// baseline (612.585 us; speedup 1.0000x reference)
//
#include <hip/hip_runtime.h>
#include <stdint.h>

typedef unsigned short u16;
typedef unsigned int u32;
typedef unsigned long long u64;
typedef __attribute__((ext_vector_type(4))) float f32x4;
typedef __attribute__((ext_vector_type(8))) short s16x8;
typedef __attribute__((ext_vector_type(4))) u16 u16x4;
typedef __attribute__((ext_vector_type(2))) u32 u32x2;
typedef __attribute__((ext_vector_type(4))) u32 u32x4;

#define NS 50
#define NH 128
#define NNODE 50000
#define TW 1152      // table row width in u16 (Gin|Gout|Ghh)
#define GSUB 3328    // bytes per staged g-subtile: 26 tiles x 128B (rows 100..103 zero)

// ---------- helpers ----------
__device__ __forceinline__ u16 f2bf(float f) {
  u32 u = __builtin_bit_cast(u32, f);
  u32 r = (u + 0x7FFFu + ((u >> 16) & 1u)) >> 16;
  return (u16)r;
}
__device__ __forceinline__ float bf2f(u16 u) {
  return __builtin_bit_cast(float, (u32)u << 16);
}
__device__ __forceinline__ float sigm(float x) {
  return 1.0f / (1.0f + __expf(-x));
}
__device__ __forceinline__ float tanh_(float x) {
  return 1.0f - 2.0f / (1.0f + __expf(2.0f * x));
}
__device__ __forceinline__ s16x8 pack8(f32x4 a, f32x4 b) {
  s16x8 r;
  r[0] = (short)f2bf(a[0]); r[1] = (short)f2bf(a[1]);
  r[2] = (short)f2bf(a[2]); r[3] = (short)f2bf(a[3]);
  r[4] = (short)f2bf(b[0]); r[5] = (short)f2bf(b[1]);
  r[6] = (short)f2bf(b[2]); r[7] = (short)f2bf(b[3]);
  return r;
}
// truncating f32->bf16 pack via v_perm (1 op / 2 elems); A in [0,1): err <= 2^-9
__device__ __forceinline__ s16x8 pack8_trunc(f32x4 a, f32x4 b) {
  u32x4 ua = __builtin_bit_cast(u32x4, a);
  u32x4 ub = __builtin_bit_cast(u32x4, b);
  u32x4 t;
  t[0] = __builtin_amdgcn_perm(ua[1], ua[0], 0x07060302u);
  t[1] = __builtin_amdgcn_perm(ua[3], ua[2], 0x07060302u);
  t[2] = __builtin_amdgcn_perm(ub[1], ub[0], 0x07060302u);
  t[3] = __builtin_amdgcn_perm(ub[3], ub[2], 0x07060302u);
  return __builtin_bit_cast(s16x8, t);
}

// batched tr-reads: all 4 kt fragments of one gate, ONE lgkmcnt(0).
// tiles: kt*8 + g4*2 for kt<3 (p0 = gb + g4*256), fixed tile 24/25 for kt=3 (p3 = gb + 3072).
__device__ __forceinline__ void afrag_tr8(const unsigned char* p0,
                                          const unsigned char* p3,
                                          s16x8 Af[4]) {
  u32x2 r0, r1, r2, r3, r4, r5, r6, r7;
  asm volatile(
      "ds_read_b64_tr_b16 %0, %8\n\t"
      "ds_read_b64_tr_b16 %1, %8 offset:128\n\t"
      "ds_read_b64_tr_b16 %2, %8 offset:1024\n\t"
      "ds_read_b64_tr_b16 %3, %8 offset:1152\n\t"
      "ds_read_b64_tr_b16 %4, %8 offset:2048\n\t"
      "ds_read_b64_tr_b16 %5, %8 offset:2176\n\t"
      "ds_read_b64_tr_b16 %6, %9\n\t"
      "ds_read_b64_tr_b16 %7, %9 offset:128\n\t"
      "s_waitcnt lgkmcnt(0)"
      : "=&v"(r0), "=&v"(r1), "=&v"(r2), "=&v"(r3),
        "=&v"(r4), "=&v"(r5), "=&v"(r6), "=&v"(r7)
      : "v"((const __attribute__((address_space(3))) unsigned char*)p0),
        "v"((const __attribute__((address_space(3))) unsigned char*)p3)
      : "memory");
  __builtin_amdgcn_sched_barrier(0);
  u32x4 t0; t0[0] = r0[0]; t0[1] = r0[1]; t0[2] = r1[0]; t0[3] = r1[1];
  u32x4 t1; t1[0] = r2[0]; t1[1] = r2[1]; t1[2] = r3[0]; t1[3] = r3[1];
  u32x4 t2; t2[0] = r4[0]; t2[1] = r4[1]; t2[2] = r5[0]; t2[3] = r5[1];
  u32x4 t3; t3[0] = r6[0]; t3[1] = r6[1]; t3[2] = r7[0]; t3[3] = r7[1];
  Af[0] = __builtin_bit_cast(s16x8, t0);
  Af[1] = __builtin_bit_cast(s16x8, t1);
  Af[2] = __builtin_bit_cast(s16x8, t2);
  Af[3] = __builtin_bit_cast(s16x8, t3);
}

// staging bijection: idx in [0,4800) -> (t in [0,100), c in [0,48))
// t = ((idx>>1)&3)*25 + (idx>>3)%25 ; c = ((idx>>3)/25)*2 + (idx&1)
// 8 consecutive lanes cover all 8 (t%4, c%2) bank-octets -> conflict-free b128 writes.
__device__ __forceinline__ void stage_decomp(int idx, int& t, int& c) {
  int e3 = idx >> 3;
  int t_hi = e3 % 25;
  int c_hi = e3 / 25;
  t = ((idx >> 1) & 3) * 25 + t_hi;
  c = c_hi * 2 + (idx & 1);
}
// staged column group gs (0..23) -> byte offset of its 16 g-cols inside Gin/Gout row
// gs = w*3 + gate  ->  g_base = gate*128 + w*16
__device__ __forceinline__ int gs_to_gbyte(int gs) {
  int wv = gs / 3, ml = gs - wv * 3;
  return (ml * 128 + wv * 16) * 2;
}

// ---------- kernel 1: fold weights -> UcatT[1152][128] bf16, cvec[3][384] f32 ----------
__global__ __launch_bounds__(256) void k1_prep(
    const float* __restrict__ W_in, const float* __restrict__ b_in,
    const float* __restrict__ W_out, const float* __restrict__ b_out,
    const float* __restrict__ w_ih, const float* __restrict__ b_ih,
    const float* __restrict__ w_hh,
    const float* __restrict__ b_iah, const float* __restrict__ b_oah,
    u16* __restrict__ UcatT, float* __restrict__ cvec)
{
  int e = blockIdx.x * 256 + threadIdx.x;
  if (e < 147456) {
    int j = e >> 7, k = e & 127;
    float s = 0.f;
    if (j < 768) {
      const float* wr = w_ih + (size_t)(j < 384 ? j : j - 384) * 256 + (j < 384 ? 0 : 128);
      const float* Wc = (j < 384 ? W_in : W_out) + k;
      #pragma unroll 8
      for (int h = 0; h < 128; ++h) s += wr[h] * Wc[h * 128];
    } else {
      s = w_hh[(size_t)(j - 768) * 128 + k];
    }
    UcatT[e] = f2bf(s);
  } else if (e < 147456 + 1152) {
    int e2 = e - 147456;
    int which = e2 / 384, g = e2 - which * 384;
    const float* wr = w_ih + (size_t)g * 256;
    float s = 0.f;
    if (which == 0) { for (int h = 0; h < 128; ++h) s += wr[h] * b_in[h]; }
    else if (which == 1) { for (int h = 0; h < 128; ++h) s += wr[128 + h] * b_out[h]; }
    else {
      for (int h = 0; h < 128; ++h) s += wr[h] * b_iah[h] + wr[128 + h] * b_oah[h];
      s += b_ih[g];
    }
    cvec[which * 384 + g] = s;
  }
}

// ---------- kernel 2: node tables T[n][1152] = emb[n] @ UcatT^T (+b_hh on Ghh part) ----------
__global__ __launch_bounds__(256, 2) void k2_tables(
    const float* __restrict__ emb, const u16* __restrict__ UcatT,
    const float* __restrict__ b_hh, u16* __restrict__ T)
{
  int tid = threadIdx.x;
  int w = tid >> 6, l = tid & 63;
  int l16 = l & 15, g4 = l >> 4;
  int n0 = blockIdx.x * 64;

  s16x8 Bf[4][4];
  #pragma unroll
  for (int nt = 0; nt < 4; ++nt) {
    int nb = n0 + nt * 16 + l16; if (nb > NNODE - 1) nb = NNODE - 1;
    const float* ep = emb + (size_t)nb * NH + g4 * 8;
    #pragma unroll
    for (int kt = 0; kt < 4; ++kt) {
      f32x4 x = *(const f32x4*)(ep + kt * 32);
      f32x4 y = *(const f32x4*)(ep + kt * 32 + 4);
      Bf[nt][kt] = pack8(x, y);
    }
  }

  for (int mt = 0; mt < 18; ++mt) {
    int j0 = w * 288 + mt * 16;
    const u16* ap = UcatT + (size_t)(j0 + l16) * 128 + g4 * 8;
    s16x8 Af[4];
    #pragma unroll
    for (int kt = 0; kt < 4; ++kt) Af[kt] = *(const s16x8*)(ap + kt * 32);

    f32x4 acc[4] = {};
    #pragma unroll
    for (int nt = 0; nt < 4; ++nt)
      #pragma unroll
      for (int kt = 0; kt < 4; ++kt)
        acc[nt] = __builtin_amdgcn_mfma_f32_16x16x32_bf16(Af[kt], Bf[nt][kt], acc[nt], 0, 0, 0);

    int jr = j0 + g4 * 4;
    f32x4 bias = {0.f, 0.f, 0.f, 0.f};
    if (jr >= 768) bias = *(const f32x4*)(b_hh + (jr - 768));
    #pragma unroll
    for (int nt = 0; nt < 4; ++nt) {
      int ns = n0 + nt * 16 + l16;
      if (ns < NNODE) {
        u32 lo = (u32)f2bf(acc[nt][0] + bias[0]) | ((u32)f2bf(acc[nt][1] + bias[1]) << 16);
        u32 hi = (u32)f2bf(acc[nt][2] + bias[2]) | ((u32)f2bf(acc[nt][3] + bias[3]) << 16);
        u32x2 v = {lo, hi};
        *(u32x2*)(T + (size_t)ns * TW + jr) = v;
      }
    }
  }
}

// ---------- kernel 3 (v4): 512 threads / 8 waves, epilogue prefetch ----------
// Wave w owns h in [16w, 16w+16) for all 3 gates (gs = w*3+gate).
// Single fat gather phase (<=10 loads/thread), one drain, two barriers total.
__global__ __launch_bounds__(512, 4) void k3_main(
    const int* __restrict__ inputs, const float* __restrict__ A,
    const u16* __restrict__ T, const float* __restrict__ cvec,
    const float* __restrict__ emb, float* __restrict__ out)
{
  __shared__ __align__(128) unsigned char Glds[24 * GSUB];  // 79872 B
  __shared__ u32 rowOff[100];     // byte offset of Gin/Gout row in T
  __shared__ int nodeIdx[64];
  __shared__ float rsLds[2][64];

  const int tid = threadIdx.x;
  const int b = blockIdx.x;
  const int w = tid >> 6, l = tid & 63;
  const int l16 = l & 15, g4 = l >> 4;

  if (tid < 64) nodeIdx[tid] = inputs[b * NS + (tid < NS ? tid : 0)];
  if (tid < 100) {
    int node = inputs[b * NS + (tid < NS ? tid : tid - NS)];
    rowOff[tid] = (u32)node * (TW * 2) + (tid < NS ? 0u : 768u);
  }
  if (tid < 128) ((float*)rsLds)[tid] = 0.f;
  // zero pad rows 100..103 (tile 25) of each gsub
  if (tid < 192) {
    int gs = tid >> 3, q = tid & 7;
    u32x4 z = {0, 0, 0, 0};
    *(u32x4*)(Glds + gs * GSUB + 3200 + q * 16) = z;
  }
  __syncthreads();

  const float* Ab = A + (size_t)b * (NS * 2 * NS);
  const char* Tb = (const char*)T;

  // ---- B-fragments straight from global A (registers, L2-hot) ----
  s16x8 Bf[4][4];
  #pragma unroll
  for (int nt = 0; nt < 4; ++nt) {
    int s = nt * 16 + l16; if (s > NS - 1) s = NS - 1;
    const float* ap = Ab + s * 100;
    #pragma unroll
    for (int kt = 0; kt < 4; ++kt) {
      f32x4 x = {0.f, 0.f, 0.f, 0.f}, y = {0.f, 0.f, 0.f, 0.f};
      if (kt < 3) {
        x = *(const f32x4*)(ap + kt * 32 + g4 * 8);
        y = *(const f32x4*)(ap + kt * 32 + g4 * 8 + 4);
      } else if (g4 == 0) {
        x = *(const f32x4*)(ap + 96);   // t 96..99; 100..103 zero
      }
      Bf[nt][kt] = pack8_trunc(x, y);
    }
  }

  // ---- issue ALL G gather loads (<=10/thread) ----
  u32x4 st[10];
  #pragma unroll
  for (int i = 0; i < 10; ++i) {
    int idx = i * 512 + tid;
    if (i < 9 || tid < 192) {
      int t, c; stage_decomp(idx, t, c);
      int gbyte = gs_to_gbyte(c >> 1) + (c & 1) * 16;
      st[i] = *(const u32x4*)(Tb + rowOff[t] + gbyte);
    }
  }

  // ---- f32 rowsums (overlapped with gather latency) ----
  if (tid < 100) {
    int s = tid < NS ? tid : tid - NS;
    const float* ap = Ab + s * 100 + (tid < NS ? 0 : NS);
    float sum = 0.f;
    #pragma unroll 10
    for (int t = 0; t < NS; ++t) sum += ap[t];
    rsLds[tid < NS ? 0 : 1][s] = sum;
  }

  // ---- write staged G to LDS ----
  #pragma unroll
  for (int i = 0; i < 10; ++i) {
    int idx = i * 512 + tid;
    if (i < 9 || tid < 192) {
      int t, c; stage_decomp(idx, t, c);
      *(u32x4*)(Glds + (c >> 1) * GSUB + t * 32 + (c & 1) * 16) = st[i];
    }
  }

  // ---- prefetch epilogue gathers (fly under the MFMA phase) ----
  const int h0 = w * 16 + g4 * 4;
  u16x4 gr[4], gi[4], gn[4];
  f32x4 hid[4];
  #pragma unroll
  for (int nt = 0; nt < 4; ++nt) {
    int s = nt * 16 + l16;
    int node = nodeIdx[s];
    const u16* Trow = T + (size_t)node * TW + 768 + h0;
    gr[nt] = *(const u16x4*)(Trow);
    gi[nt] = *(const u16x4*)(Trow + 128);
    gn[nt] = *(const u16x4*)(Trow + 256);
    hid[nt] = *(const f32x4*)(emb + (size_t)node * NH + h0);
  }
  __syncthreads();

  // ---- MFMA: 3 gates for this wave's h-slice ----
  const s16x8 zero8 = {0, 0, 0, 0, 0, 0, 0, 0};
  f32x4 acc[3][4] = {};
  #pragma unroll
  for (int gate = 0; gate < 3; ++gate) {
    const int gs = w * 3 + gate;
    const unsigned char* gb = Glds + gs * GSUB + l16 * 8;
    s16x8 Af[4];
    afrag_tr8(gb + g4 * 256, gb + 3072, Af);
    if (g4 != 0) Af[3] = zero8;
    #pragma unroll
    for (int kt = 0; kt < 4; ++kt)
      #pragma unroll
      for (int nt = 0; nt < 4; ++nt)
        acc[gate][nt] = __builtin_amdgcn_mfma_f32_16x16x32_bf16(Af[kt], Bf[nt][kt], acc[gate][nt], 0, 0, 0);
  }

  // ---- GRU epilogue ----
  f32x4 cin[3], cou[3], cz[3];
  #pragma unroll
  for (int gate = 0; gate < 3; ++gate) {
    int g = gate * 128 + h0;
    cin[gate] = *(const f32x4*)(cvec + g);
    cou[gate] = *(const f32x4*)(cvec + 384 + g);
    cz[gate]  = *(const f32x4*)(cvec + 768 + g);
  }
  #pragma unroll
  for (int nt = 0; nt < 4; ++nt) {
    int s = nt * 16 + l16;
    float rin = rsLds[0][s], rou = rsLds[1][s];
    f32x4 res;
    #pragma unroll
    for (int r = 0; r < 4; ++r) {
      float vr = acc[0][nt][r] + rin * cin[0][r] + rou * cou[0][r] + cz[0][r] + bf2f(gr[nt][r]);
      float vi = acc[1][nt][r] + rin * cin[1][r] + rou * cou[1][r] + cz[1][r] + bf2f(gi[nt][r]);
      float vn = acc[2][nt][r] + rin * cin[2][r] + rou * cou[2][r] + cz[2][r];
      float rr = sigm(vr);
      float ii = sigm(vi);
      float nn = tanh_(vn + rr * bf2f(gn[nt][r]));
      res[r] = nn + ii * (hid[nt][r] - nn);
    }
    if (s < NS)
      *(f32x4*)(out + ((size_t)b * NS + s) * NH + h0) = res;
  }
}

// ---------- launcher ----------
extern "C" void kernel_launch(void* const* d_in, const int* in_sizes, int n_in,
                              void* d_out, int out_size, void* d_ws, size_t ws_size,
                              hipStream_t stream) {
  const int*   inputs = (const int*)  d_in[0];
  const float* A      = (const float*)d_in[1];
  const float* emb    = (const float*)d_in[2];
  const float* W_in   = (const float*)d_in[3];
  const float* b_in   = (const float*)d_in[4];
  const float* W_out  = (const float*)d_in[5];
  const float* b_out  = (const float*)d_in[6];
  const float* w_ih   = (const float*)d_in[7];
  const float* b_ih   = (const float*)d_in[8];
  const float* w_hh   = (const float*)d_in[9];
  const float* b_hh   = (const float*)d_in[10];
  const float* b_iah  = (const float*)d_in[11];
  const float* b_oah  = (const float*)d_in[12];

  // ws layout: T (50000*1152 bf16 = 115,200,000 B) | UcatT (294,912 B) | cvec (4,608 B)
  u16*   T     = (u16*)d_ws;
  u16*   UcatT = (u16*)((char*)d_ws + 115200000);
  float* cvec  = (float*)((char*)d_ws + 115200000 + 294912);

  k1_prep<<<dim3(581), dim3(256), 0, stream>>>(W_in, b_in, W_out, b_out, w_ih, b_ih,
                                               w_hh, b_iah, b_oah, UcatT, cvec);
  k2_tables<<<dim3(782), dim3(256), 0, stream>>>(emb, UcatT, b_hh, T);
  k3_main<<<dim3(4096), dim3(512), 0, stream>>>(inputs, A, T, cvec, emb, (float*)d_out);
}

// Round 7
// 345.472 us; speedup vs baseline: 1.7732x; 1.7732x over previous
//
#include <hip/hip_runtime.h>
#include <stdint.h>

typedef unsigned short u16;
typedef unsigned int u32;
typedef unsigned long long u64;
typedef __attribute__((ext_vector_type(4))) float f32x4;
typedef __attribute__((ext_vector_type(8))) short s16x8;
typedef __attribute__((ext_vector_type(4))) u16 u16x4;
typedef __attribute__((ext_vector_type(2))) u32 u32x2;
typedef __attribute__((ext_vector_type(4))) u32 u32x4;

#define NS 50
#define NH 128
#define NNODE 50000
#define TW 1152      // table row width in u16 (Gin|Gout|Ghh)
#define GSUB 3328    // bytes per staged g-subtile: 26 tiles x 128B (rows 100..103 zero)

// ---------- helpers ----------
__device__ __forceinline__ u16 f2bf(float f) {
  u32 u = __builtin_bit_cast(u32, f);
  u32 r = (u + 0x7FFFu + ((u >> 16) & 1u)) >> 16;
  return (u16)r;
}
__device__ __forceinline__ float bf2f(u16 u) {
  return __builtin_bit_cast(float, (u32)u << 16);
}
__device__ __forceinline__ float sigm(float x) {
  return 1.0f / (1.0f + __expf(-x));
}
__device__ __forceinline__ float tanh_(float x) {
  return 1.0f - 2.0f / (1.0f + __expf(2.0f * x));
}
__device__ __forceinline__ s16x8 pack8(f32x4 a, f32x4 b) {
  s16x8 r;
  r[0] = (short)f2bf(a[0]); r[1] = (short)f2bf(a[1]);
  r[2] = (short)f2bf(a[2]); r[3] = (short)f2bf(a[3]);
  r[4] = (short)f2bf(b[0]); r[5] = (short)f2bf(b[1]);
  r[6] = (short)f2bf(b[2]); r[7] = (short)f2bf(b[3]);
  return r;
}
// truncating f32->bf16 pack via v_perm (1 op / 2 elems); A in [0,1): err <= 2^-9
__device__ __forceinline__ s16x8 pack8_trunc(f32x4 a, f32x4 b) {
  u32x4 ua = __builtin_bit_cast(u32x4, a);
  u32x4 ub = __builtin_bit_cast(u32x4, b);
  u32x4 t;
  t[0] = __builtin_amdgcn_perm(ua[1], ua[0], 0x07060302u);
  t[1] = __builtin_amdgcn_perm(ua[3], ua[2], 0x07060302u);
  t[2] = __builtin_amdgcn_perm(ub[1], ub[0], 0x07060302u);
  t[3] = __builtin_amdgcn_perm(ub[3], ub[2], 0x07060302u);
  return __builtin_bit_cast(s16x8, t);
}

// batched tr-reads: all 4 kt fragments of one gate, ONE lgkmcnt(0).
// tiles: kt*8 + g4*2 for kt<3 (p0 = gb + g4*256), fixed tile 24/25 for kt=3 (p3 = gb + 3072).
__device__ __forceinline__ void afrag_tr8(const unsigned char* p0,
                                          const unsigned char* p3,
                                          s16x8 Af[4]) {
  u32x2 r0, r1, r2, r3, r4, r5, r6, r7;
  asm volatile(
      "ds_read_b64_tr_b16 %0, %8\n\t"
      "ds_read_b64_tr_b16 %1, %8 offset:128\n\t"
      "ds_read_b64_tr_b16 %2, %8 offset:1024\n\t"
      "ds_read_b64_tr_b16 %3, %8 offset:1152\n\t"
      "ds_read_b64_tr_b16 %4, %8 offset:2048\n\t"
      "ds_read_b64_tr_b16 %5, %8 offset:2176\n\t"
      "ds_read_b64_tr_b16 %6, %9\n\t"
      "ds_read_b64_tr_b16 %7, %9 offset:128\n\t"
      "s_waitcnt lgkmcnt(0)"
      : "=&v"(r0), "=&v"(r1), "=&v"(r2), "=&v"(r3),
        "=&v"(r4), "=&v"(r5), "=&v"(r6), "=&v"(r7)
      : "v"((const __attribute__((address_space(3))) unsigned char*)p0),
        "v"((const __attribute__((address_space(3))) unsigned char*)p3)
      : "memory");
  __builtin_amdgcn_sched_barrier(0);
  u32x4 t0; t0[0] = r0[0]; t0[1] = r0[1]; t0[2] = r1[0]; t0[3] = r1[1];
  u32x4 t1; t1[0] = r2[0]; t1[1] = r2[1]; t1[2] = r3[0]; t1[3] = r3[1];
  u32x4 t2; t2[0] = r4[0]; t2[1] = r4[1]; t2[2] = r5[0]; t2[3] = r5[1];
  u32x4 t3; t3[0] = r6[0]; t3[1] = r6[1]; t3[2] = r7[0]; t3[3] = r7[1];
  Af[0] = __builtin_bit_cast(s16x8, t0);
  Af[1] = __builtin_bit_cast(s16x8, t1);
  Af[2] = __builtin_bit_cast(s16x8, t2);
  Af[3] = __builtin_bit_cast(s16x8, t3);
}

// staging bijection: idx in [0,4800) -> (t in [0,100), c in [0,48))
// t = ((idx>>1)&3)*25 + (idx>>3)%25 ; c = ((idx>>3)/25)*2 + (idx&1)
// 8 consecutive lanes cover all 8 (t%4, c%2) bank-octets -> conflict-free b128 writes.
__device__ __forceinline__ void stage_decomp(int idx, int& t, int& c) {
  int e3 = idx >> 3;
  int t_hi = e3 % 25;
  int c_hi = e3 / 25;
  t = ((idx >> 1) & 3) * 25 + t_hi;
  c = c_hi * 2 + (idx & 1);
}
// staged column group gs (0..23) -> byte offset of its 16 g-cols inside Gin/Gout row
// gs = w*3 + gate  ->  g_base = gate*128 + w*16
__device__ __forceinline__ int gs_to_gbyte(int gs) {
  int wv = gs / 3, ml = gs - wv * 3;
  return (ml * 128 + wv * 16) * 2;
}

// ---------- kernel 1: fold weights -> UcatT[1152][128] bf16, cvec[3][384] f32 ----------
__global__ __launch_bounds__(256) void k1_prep(
    const float* __restrict__ W_in, const float* __restrict__ b_in,
    const float* __restrict__ W_out, const float* __restrict__ b_out,
    const float* __restrict__ w_ih, const float* __restrict__ b_ih,
    const float* __restrict__ w_hh,
    const float* __restrict__ b_iah, const float* __restrict__ b_oah,
    u16* __restrict__ UcatT, float* __restrict__ cvec)
{
  int e = blockIdx.x * 256 + threadIdx.x;
  if (e < 147456) {
    int j = e >> 7, k = e & 127;
    float s = 0.f;
    if (j < 768) {
      const float* wr = w_ih + (size_t)(j < 384 ? j : j - 384) * 256 + (j < 384 ? 0 : 128);
      const float* Wc = (j < 384 ? W_in : W_out) + k;
      #pragma unroll 8
      for (int h = 0; h < 128; ++h) s += wr[h] * Wc[h * 128];
    } else {
      s = w_hh[(size_t)(j - 768) * 128 + k];
    }
    UcatT[e] = f2bf(s);
  } else if (e < 147456 + 1152) {
    int e2 = e - 147456;
    int which = e2 / 384, g = e2 - which * 384;
    const float* wr = w_ih + (size_t)g * 256;
    float s = 0.f;
    if (which == 0) { for (int h = 0; h < 128; ++h) s += wr[h] * b_in[h]; }
    else if (which == 1) { for (int h = 0; h < 128; ++h) s += wr[128 + h] * b_out[h]; }
    else {
      for (int h = 0; h < 128; ++h) s += wr[h] * b_iah[h] + wr[128 + h] * b_oah[h];
      s += b_ih[g];
    }
    cvec[which * 384 + g] = s;
  }
}

// ---------- kernel 2: node tables T[n][1152] = emb[n] @ UcatT^T (+b_hh on Ghh part) ----------
__global__ __launch_bounds__(256, 2) void k2_tables(
    const float* __restrict__ emb, const u16* __restrict__ UcatT,
    const float* __restrict__ b_hh, u16* __restrict__ T)
{
  int tid = threadIdx.x;
  int w = tid >> 6, l = tid & 63;
  int l16 = l & 15, g4 = l >> 4;
  int n0 = blockIdx.x * 64;

  s16x8 Bf[4][4];
  #pragma unroll
  for (int nt = 0; nt < 4; ++nt) {
    int nb = n0 + nt * 16 + l16; if (nb > NNODE - 1) nb = NNODE - 1;
    const float* ep = emb + (size_t)nb * NH + g4 * 8;
    #pragma unroll
    for (int kt = 0; kt < 4; ++kt) {
      f32x4 x = *(const f32x4*)(ep + kt * 32);
      f32x4 y = *(const f32x4*)(ep + kt * 32 + 4);
      Bf[nt][kt] = pack8(x, y);
    }
  }

  for (int mt = 0; mt < 18; ++mt) {
    int j0 = w * 288 + mt * 16;
    const u16* ap = UcatT + (size_t)(j0 + l16) * 128 + g4 * 8;
    s16x8 Af[4];
    #pragma unroll
    for (int kt = 0; kt < 4; ++kt) Af[kt] = *(const s16x8*)(ap + kt * 32);

    f32x4 acc[4] = {};
    #pragma unroll
    for (int nt = 0; nt < 4; ++nt)
      #pragma unroll
      for (int kt = 0; kt < 4; ++kt)
        acc[nt] = __builtin_amdgcn_mfma_f32_16x16x32_bf16(Af[kt], Bf[nt][kt], acc[nt], 0, 0, 0);

    int jr = j0 + g4 * 4;
    f32x4 bias = {0.f, 0.f, 0.f, 0.f};
    if (jr >= 768) bias = *(const f32x4*)(b_hh + (jr - 768));
    #pragma unroll
    for (int nt = 0; nt < 4; ++nt) {
      int ns = n0 + nt * 16 + l16;
      if (ns < NNODE) {
        u32 lo = (u32)f2bf(acc[nt][0] + bias[0]) | ((u32)f2bf(acc[nt][1] + bias[1]) << 16);
        u32 hi = (u32)f2bf(acc[nt][2] + bias[2]) | ((u32)f2bf(acc[nt][3] + bias[3]) << 16);
        u32x2 v = {lo, hi};
        *(u32x2*)(T + (size_t)ns * TW + jr) = v;
      }
    }
  }
}

// ---------- kernel 3 (v5): 512 threads / 8 waves, launch_bounds(512,2) — no spill ----------
// Wave w owns h in [16w, 16w+16) for all 3 gates (gs = w*3+gate).
// Single fat gather phase (<=10 loads/thread), one drain, two barriers total.
// Epilogue gathers post-MFMA (L2-hot) to keep peak VGPR liveness <= ~128.
__global__ __launch_bounds__(512, 2) void k3_main(
    const int* __restrict__ inputs, const float* __restrict__ A,
    const u16* __restrict__ T, const float* __restrict__ cvec,
    const float* __restrict__ emb, float* __restrict__ out)
{
  __shared__ __align__(128) unsigned char Glds[24 * GSUB];  // 79872 B
  __shared__ u32 rowOff[100];     // byte offset of Gin/Gout row in T
  __shared__ int nodeIdx[64];
  __shared__ float rsLds[2][64];

  const int tid = threadIdx.x;
  const int b = blockIdx.x;
  const int w = tid >> 6, l = tid & 63;
  const int l16 = l & 15, g4 = l >> 4;

  if (tid < 64) nodeIdx[tid] = inputs[b * NS + (tid < NS ? tid : 0)];
  if (tid < 100) {
    int node = inputs[b * NS + (tid < NS ? tid : tid - NS)];
    rowOff[tid] = (u32)node * (TW * 2) + (tid < NS ? 0u : 768u);
  }
  if (tid < 128) ((float*)rsLds)[tid] = 0.f;
  // zero pad rows 100..103 (tile 25) of each gsub
  if (tid < 192) {
    int gs = tid >> 3, q = tid & 7;
    u32x4 z = {0, 0, 0, 0};
    *(u32x4*)(Glds + gs * GSUB + 3200 + q * 16) = z;
  }
  __syncthreads();

  const float* Ab = A + (size_t)b * (NS * 2 * NS);
  const char* Tb = (const char*)T;

  // ---- issue ALL G gather loads (<=10/thread) ----
  u32x4 st[10];
  #pragma unroll
  for (int i = 0; i < 10; ++i) {
    int idx = i * 512 + tid;
    if (i < 9 || tid < 192) {
      int t, c; stage_decomp(idx, t, c);
      int gbyte = gs_to_gbyte(c >> 1) + (c & 1) * 16;
      st[i] = *(const u32x4*)(Tb + rowOff[t] + gbyte);
    }
  }

  // ---- f32 rowsums (overlapped with gather latency) ----
  if (tid < 100) {
    int s = tid < NS ? tid : tid - NS;
    const float* ap = Ab + s * 100 + (tid < NS ? 0 : NS);
    float sum = 0.f;
    #pragma unroll 10
    for (int t = 0; t < NS; ++t) sum += ap[t];
    rsLds[tid < NS ? 0 : 1][s] = sum;
  }

  // ---- write staged G to LDS (frees st before Bf loads) ----
  #pragma unroll
  for (int i = 0; i < 10; ++i) {
    int idx = i * 512 + tid;
    if (i < 9 || tid < 192) {
      int t, c; stage_decomp(idx, t, c);
      *(u32x4*)(Glds + (c >> 1) * GSUB + t * 32 + (c & 1) * 16) = st[i];
    }
  }

  // ---- B-fragments straight from global A (registers, L2-hot) ----
  s16x8 Bf[4][4];
  #pragma unroll
  for (int nt = 0; nt < 4; ++nt) {
    int s = nt * 16 + l16; if (s > NS - 1) s = NS - 1;
    const float* ap = Ab + s * 100;
    #pragma unroll
    for (int kt = 0; kt < 4; ++kt) {
      f32x4 x = {0.f, 0.f, 0.f, 0.f}, y = {0.f, 0.f, 0.f, 0.f};
      if (kt < 3) {
        x = *(const f32x4*)(ap + kt * 32 + g4 * 8);
        y = *(const f32x4*)(ap + kt * 32 + g4 * 8 + 4);
      } else if (g4 == 0) {
        x = *(const f32x4*)(ap + 96);   // t 96..99; 100..103 zero
      }
      Bf[nt][kt] = pack8_trunc(x, y);
    }
  }
  __syncthreads();

  // ---- MFMA: 3 gates for this wave's h-slice ----
  const s16x8 zero8 = {0, 0, 0, 0, 0, 0, 0, 0};
  f32x4 acc[3][4] = {};
  #pragma unroll
  for (int gate = 0; gate < 3; ++gate) {
    const int gs = w * 3 + gate;
    const unsigned char* gb = Glds + gs * GSUB + l16 * 8;
    s16x8 Af[4];
    afrag_tr8(gb + g4 * 256, gb + 3072, Af);
    if (g4 != 0) Af[3] = zero8;
    #pragma unroll
    for (int kt = 0; kt < 4; ++kt)
      #pragma unroll
      for (int nt = 0; nt < 4; ++nt)
        acc[gate][nt] = __builtin_amdgcn_mfma_f32_16x16x32_bf16(Af[kt], Bf[nt][kt], acc[gate][nt], 0, 0, 0);
  }

  // ---- GRU epilogue (gathers post-MFMA; Ghh rows L2-hot from staging) ----
  const int h0 = w * 16 + g4 * 4;
  f32x4 cin[3], cou[3], cz[3];
  #pragma unroll
  for (int gate = 0; gate < 3; ++gate) {
    int g = gate * 128 + h0;
    cin[gate] = *(const f32x4*)(cvec + g);
    cou[gate] = *(const f32x4*)(cvec + 384 + g);
    cz[gate]  = *(const f32x4*)(cvec + 768 + g);
  }
  #pragma unroll
  for (int nt = 0; nt < 4; ++nt) {
    int s = nt * 16 + l16;
    int node = nodeIdx[s];
    const u16* Trow = T + (size_t)node * TW + 768 + h0;
    u16x4 gr = *(const u16x4*)(Trow);
    u16x4 gi = *(const u16x4*)(Trow + 128);
    u16x4 gn = *(const u16x4*)(Trow + 256);
    f32x4 hid = *(const f32x4*)(emb + (size_t)node * NH + h0);
    float rin = rsLds[0][s], rou = rsLds[1][s];
    f32x4 res;
    #pragma unroll
    for (int r = 0; r < 4; ++r) {
      float vr = acc[0][nt][r] + rin * cin[0][r] + rou * cou[0][r] + cz[0][r] + bf2f(gr[r]);
      float vi = acc[1][nt][r] + rin * cin[1][r] + rou * cou[1][r] + cz[1][r] + bf2f(gi[r]);
      float vn = acc[2][nt][r] + rin * cin[2][r] + rou * cou[2][r] + cz[2][r];
      float rr = sigm(vr);
      float ii = sigm(vi);
      float nn = tanh_(vn + rr * bf2f(gn[r]));
      res[r] = nn + ii * (hid[r] - nn);
    }
    if (s < NS)
      *(f32x4*)(out + ((size_t)b * NS + s) * NH + h0) = res;
  }
}

// ---------- launcher ----------
extern "C" void kernel_launch(void* const* d_in, const int* in_sizes, int n_in,
                              void* d_out, int out_size, void* d_ws, size_t ws_size,
                              hipStream_t stream) {
  const int*   inputs = (const int*)  d_in[0];
  const float* A      = (const float*)d_in[1];
  const float* emb    = (const float*)d_in[2];
  const float* W_in   = (const float*)d_in[3];
  const float* b_in   = (const float*)d_in[4];
  const float* W_out  = (const float*)d_in[5];
  const float* b_out  = (const float*)d_in[6];
  const float* w_ih   = (const float*)d_in[7];
  const float* b_ih   = (const float*)d_in[8];
  const float* w_hh   = (const float*)d_in[9];
  const float* b_hh   = (const float*)d_in[10];
  const float* b_iah  = (const float*)d_in[11];
  const float* b_oah  = (const float*)d_in[12];

  // ws layout: T (50000*1152 bf16 = 115,200,000 B) | UcatT (294,912 B) | cvec (4,608 B)
  u16*   T     = (u16*)d_ws;
  u16*   UcatT = (u16*)((char*)d_ws + 115200000);
  float* cvec  = (float*)((char*)d_ws + 115200000 + 294912);

  k1_prep<<<dim3(581), dim3(256), 0, stream>>>(W_in, b_in, W_out, b_out, w_ih, b_ih,
                                               w_hh, b_iah, b_oah, UcatT, cvec);
  k2_tables<<<dim3(782), dim3(256), 0, stream>>>(emb, UcatT, b_hh, T);
  k3_main<<<dim3(4096), dim3(512), 0, stream>>>(inputs, A, T, cvec, emb, (float*)d_out);
}

// Round 8
// 315.703 us; speedup vs baseline: 1.9404x; 1.0943x over previous
//
#include <hip/hip_runtime.h>
#include <stdint.h>

typedef unsigned short u16;
typedef unsigned int u32;
typedef unsigned long long u64;
typedef __attribute__((ext_vector_type(4))) float f32x4;
typedef __attribute__((ext_vector_type(8))) short s16x8;
typedef __attribute__((ext_vector_type(4))) u16 u16x4;
typedef __attribute__((ext_vector_type(2))) u32 u32x2;
typedef __attribute__((ext_vector_type(4))) u32 u32x4;

#define NS 50
#define NH 128
#define NNODE 50000
#define TW 1152      // table row width in u16 (Gin|Gout|Ghh)
#define GSUB 3328    // bytes per staged g-subtile: 26 tiles x 128B (rows 100..103 zero)

// ---------- helpers ----------
__device__ __forceinline__ u16 f2bf(float f) {
  u32 u = __builtin_bit_cast(u32, f);
  u32 r = (u + 0x7FFFu + ((u >> 16) & 1u)) >> 16;
  return (u16)r;
}
__device__ __forceinline__ float bf2f(u16 u) {
  return __builtin_bit_cast(float, (u32)u << 16);
}
__device__ __forceinline__ float sigm(float x) {
  return 1.0f / (1.0f + __expf(-x));
}
__device__ __forceinline__ float tanh_(float x) {
  return 1.0f - 2.0f / (1.0f + __expf(2.0f * x));
}
__device__ __forceinline__ s16x8 pack8(f32x4 a, f32x4 b) {
  s16x8 r;
  r[0] = (short)f2bf(a[0]); r[1] = (short)f2bf(a[1]);
  r[2] = (short)f2bf(a[2]); r[3] = (short)f2bf(a[3]);
  r[4] = (short)f2bf(b[0]); r[5] = (short)f2bf(b[1]);
  r[6] = (short)f2bf(b[2]); r[7] = (short)f2bf(b[3]);
  return r;
}
// truncating f32->bf16 pack via v_perm (1 op / 2 elems); A in [0,1): err <= 2^-9
__device__ __forceinline__ s16x8 pack8_trunc(f32x4 a, f32x4 b) {
  u32x4 ua = __builtin_bit_cast(u32x4, a);
  u32x4 ub = __builtin_bit_cast(u32x4, b);
  u32x4 t;
  t[0] = __builtin_amdgcn_perm(ua[1], ua[0], 0x07060302u);
  t[1] = __builtin_amdgcn_perm(ua[3], ua[2], 0x07060302u);
  t[2] = __builtin_amdgcn_perm(ub[1], ub[0], 0x07060302u);
  t[3] = __builtin_amdgcn_perm(ub[3], ub[2], 0x07060302u);
  return __builtin_bit_cast(s16x8, t);
}

// batched tr-reads: all 4 kt fragments of one gate, ONE lgkmcnt(0).
// tiles: kt*8 + g4*2 for kt<3 (p0 = gb + g4*256), fixed tile 24/25 for kt=3 (p3 = gb + 3072).
__device__ __forceinline__ void afrag_tr8(const unsigned char* p0,
                                          const unsigned char* p3,
                                          s16x8 Af[4]) {
  u32x2 r0, r1, r2, r3, r4, r5, r6, r7;
  asm volatile(
      "ds_read_b64_tr_b16 %0, %8\n\t"
      "ds_read_b64_tr_b16 %1, %8 offset:128\n\t"
      "ds_read_b64_tr_b16 %2, %8 offset:1024\n\t"
      "ds_read_b64_tr_b16 %3, %8 offset:1152\n\t"
      "ds_read_b64_tr_b16 %4, %8 offset:2048\n\t"
      "ds_read_b64_tr_b16 %5, %8 offset:2176\n\t"
      "ds_read_b64_tr_b16 %6, %9\n\t"
      "ds_read_b64_tr_b16 %7, %9 offset:128\n\t"
      "s_waitcnt lgkmcnt(0)"
      : "=&v"(r0), "=&v"(r1), "=&v"(r2), "=&v"(r3),
        "=&v"(r4), "=&v"(r5), "=&v"(r6), "=&v"(r7)
      : "v"((const __attribute__((address_space(3))) unsigned char*)p0),
        "v"((const __attribute__((address_space(3))) unsigned char*)p3)
      : "memory");
  __builtin_amdgcn_sched_barrier(0);
  u32x4 t0; t0[0] = r0[0]; t0[1] = r0[1]; t0[2] = r1[0]; t0[3] = r1[1];
  u32x4 t1; t1[0] = r2[0]; t1[1] = r2[1]; t1[2] = r3[0]; t1[3] = r3[1];
  u32x4 t2; t2[0] = r4[0]; t2[1] = r4[1]; t2[2] = r5[0]; t2[3] = r5[1];
  u32x4 t3; t3[0] = r6[0]; t3[1] = r6[1]; t3[2] = r7[0]; t3[3] = r7[1];
  Af[0] = __builtin_bit_cast(s16x8, t0);
  Af[1] = __builtin_bit_cast(s16x8, t1);
  Af[2] = __builtin_bit_cast(s16x8, t2);
  Af[3] = __builtin_bit_cast(s16x8, t3);
}

// staging bijection: idx in [0,2400) -> (t in [0,100), gs in [0,12), lo in {0,1})
//   e3 = idx>>3; gs = e3/25; t = ((idx>>1)&3)*25 + e3%25; lo = idx&1
// 8 consecutive lanes hit 8 distinct LDS bank-octets -> conflict-free b128 writes.
__device__ __forceinline__ void stage_decomp(int idx, int& t, int& gs, int& lo) {
  int e3 = idx >> 3;
  gs = e3 / 25;
  t = ((idx >> 1) & 3) * 25 + (e3 - gs * 25);
  lo = idx & 1;
}

// ---------- kernel 1: fold weights -> UcatT[1152][128] bf16, cvec[3][384] f32 ----------
__global__ __launch_bounds__(256) void k1_prep(
    const float* __restrict__ W_in, const float* __restrict__ b_in,
    const float* __restrict__ W_out, const float* __restrict__ b_out,
    const float* __restrict__ w_ih, const float* __restrict__ b_ih,
    const float* __restrict__ w_hh,
    const float* __restrict__ b_iah, const float* __restrict__ b_oah,
    u16* __restrict__ UcatT, float* __restrict__ cvec)
{
  int e = blockIdx.x * 256 + threadIdx.x;
  if (e < 147456) {
    int j = e >> 7, k = e & 127;
    float s = 0.f;
    if (j < 768) {
      const float* wr = w_ih + (size_t)(j < 384 ? j : j - 384) * 256 + (j < 384 ? 0 : 128);
      const float* Wc = (j < 384 ? W_in : W_out) + k;
      #pragma unroll 8
      for (int h = 0; h < 128; ++h) s += wr[h] * Wc[h * 128];
    } else {
      s = w_hh[(size_t)(j - 768) * 128 + k];
    }
    UcatT[e] = f2bf(s);
  } else if (e < 147456 + 1152) {
    int e2 = e - 147456;
    int which = e2 / 384, g = e2 - which * 384;
    const float* wr = w_ih + (size_t)g * 256;
    float s = 0.f;
    if (which == 0) { for (int h = 0; h < 128; ++h) s += wr[h] * b_in[h]; }
    else if (which == 1) { for (int h = 0; h < 128; ++h) s += wr[128 + h] * b_out[h]; }
    else {
      for (int h = 0; h < 128; ++h) s += wr[h] * b_iah[h] + wr[128 + h] * b_oah[h];
      s += b_ih[g];
    }
    cvec[which * 384 + g] = s;
  }
}

// ---------- kernel 2: node tables T[n][1152] = emb[n] @ UcatT^T (+b_hh on Ghh part) ----------
__global__ __launch_bounds__(256, 2) void k2_tables(
    const float* __restrict__ emb, const u16* __restrict__ UcatT,
    const float* __restrict__ b_hh, u16* __restrict__ T)
{
  int tid = threadIdx.x;
  int w = tid >> 6, l = tid & 63;
  int l16 = l & 15, g4 = l >> 4;
  int n0 = blockIdx.x * 64;

  s16x8 Bf[4][4];
  #pragma unroll
  for (int nt = 0; nt < 4; ++nt) {
    int nb = n0 + nt * 16 + l16; if (nb > NNODE - 1) nb = NNODE - 1;
    const float* ep = emb + (size_t)nb * NH + g4 * 8;
    #pragma unroll
    for (int kt = 0; kt < 4; ++kt) {
      f32x4 x = *(const f32x4*)(ep + kt * 32);
      f32x4 y = *(const f32x4*)(ep + kt * 32 + 4);
      Bf[nt][kt] = pack8(x, y);
    }
  }

  for (int mt = 0; mt < 18; ++mt) {
    int j0 = w * 288 + mt * 16;
    const u16* ap = UcatT + (size_t)(j0 + l16) * 128 + g4 * 8;
    s16x8 Af[4];
    #pragma unroll
    for (int kt = 0; kt < 4; ++kt) Af[kt] = *(const s16x8*)(ap + kt * 32);

    f32x4 acc[4] = {};
    #pragma unroll
    for (int nt = 0; nt < 4; ++nt)
      #pragma unroll
      for (int kt = 0; kt < 4; ++kt)
        acc[nt] = __builtin_amdgcn_mfma_f32_16x16x32_bf16(Af[kt], Bf[nt][kt], acc[nt], 0, 0, 0);

    int jr = j0 + g4 * 4;
    f32x4 bias = {0.f, 0.f, 0.f, 0.f};
    if (jr >= 768) bias = *(const f32x4*)(b_hh + (jr - 768));
    #pragma unroll
    for (int nt = 0; nt < 4; ++nt) {
      int ns = n0 + nt * 16 + l16;
      if (ns < NNODE) {
        u32 lo = (u32)f2bf(acc[nt][0] + bias[0]) | ((u32)f2bf(acc[nt][1] + bias[1]) << 16);
        u32 hi = (u32)f2bf(acc[nt][2] + bias[2]) | ((u32)f2bf(acc[nt][3] + bias[3]) << 16);
        u32x2 v = {lo, hi};
        *(u32x2*)(T + (size_t)ns * TW + jr) = v;
      }
    }
  }
}

// ---------- kernel 3 (v6): h-split blocks, 256 thr / 4 waves, 40.4 KB LDS -> 4 blocks/CU ----------
// blockIdx = b*2 + half; block owns h in [half*64, half*64+64) for all 3 gates.
// Wave w owns h-slice [half*64 + 16w, +16); subtile gs = gate*4 + w.
// Single gather phase (<=10 loads/thread), one drain, one barrier. No rowOff/nodeIdx LDS.
__global__ __launch_bounds__(256, 2) void k3_main(
    const int* __restrict__ inputs, const float* __restrict__ A,
    const u16* __restrict__ T, const float* __restrict__ cvec,
    const float* __restrict__ emb, float* __restrict__ out)
{
  __shared__ __align__(128) unsigned char Glds[12 * GSUB];  // 39936 B
  __shared__ float rsLds[2][64];                            // 512 B

  const int tid = threadIdx.x;
  const int b = blockIdx.x >> 1;
  const int half = blockIdx.x & 1;
  const int w = tid >> 6, l = tid & 63;
  const int l16 = l & 15, g4 = l >> 4;

  const float* Ab = A + (size_t)b * (NS * 2 * NS);
  const int* inp = inputs + b * NS;
  const char* Tb = (const char*)T;

  if (tid < 128) ((float*)rsLds)[tid] = 0.f;

  // ---- B-fragments straight from global A (registers; issued first) ----
  s16x8 Bf[4][4];
  #pragma unroll
  for (int nt = 0; nt < 4; ++nt) {
    int s = nt * 16 + l16; if (s > NS - 1) s = NS - 1;
    const float* ap = Ab + s * 100;
    #pragma unroll
    for (int kt = 0; kt < 4; ++kt) {
      f32x4 x = {0.f, 0.f, 0.f, 0.f}, y = {0.f, 0.f, 0.f, 0.f};
      if (kt < 3) {
        x = *(const f32x4*)(ap + kt * 32 + g4 * 8);
        y = *(const f32x4*)(ap + kt * 32 + g4 * 8 + 4);
      } else if (g4 == 0) {
        x = *(const f32x4*)(ap + 96);   // t 96..99; 100..103 zero
      }
      Bf[nt][kt] = pack8_trunc(x, y);
    }
  }

  // ---- issue G gather loads for this h-half (<=10/thread) ----
  u32x4 st[10];
  #pragma unroll
  for (int i = 0; i < 10; ++i) {
    int idx = i * 256 + tid;
    if (i < 9 || tid < 96) {
      int t, gs, lo; stage_decomp(idx, t, gs, lo);
      int node = inp[t < NS ? t : t - NS];
      u32 ro = (u32)node * (TW * 2) + (t < NS ? 0u : 768u);
      int gate = gs >> 2, wv = gs & 3;
      int gbyte = gate * 256 + half * 128 + wv * 32 + lo * 16;
      st[i] = *(const u32x4*)(Tb + ro + gbyte);
    }
  }

  // ---- f32 rowsums (overlap gather latency; A slice L1/L2-hot from Bf reads) ----
  if (tid < 100) {
    int s = tid < NS ? tid : tid - NS;
    const float* ap = Ab + s * 100 + (tid < NS ? 0 : NS);
    float sum = 0.f;
    #pragma unroll 10
    for (int t = 0; t < NS; ++t) sum += ap[t];
    rsLds[tid < NS ? 0 : 1][s] = sum;
  }

  // ---- zero pad tiles (t 100..103 of each gsub) ----
  if (tid < 96) {
    int gs = tid >> 3, q = tid & 7;
    u32x4 z = {0, 0, 0, 0};
    *(u32x4*)(Glds + gs * GSUB + 3200 + q * 16) = z;
  }

  // ---- write staged G to LDS (vmcnt drain) ----
  #pragma unroll
  for (int i = 0; i < 10; ++i) {
    int idx = i * 256 + tid;
    if (i < 9 || tid < 96) {
      int t, gs, lo; stage_decomp(idx, t, gs, lo);
      *(u32x4*)(Glds + gs * GSUB + t * 32 + lo * 16) = st[i];
    }
  }
  __syncthreads();

  // ---- MFMA: 3 gates for this wave's h-slice ----
  const s16x8 zero8 = {0, 0, 0, 0, 0, 0, 0, 0};
  f32x4 acc[3][4] = {};
  #pragma unroll
  for (int gate = 0; gate < 3; ++gate) {
    const int gs = gate * 4 + w;
    const unsigned char* gb = Glds + gs * GSUB + l16 * 8;
    s16x8 Af[4];
    afrag_tr8(gb + g4 * 256, gb + 3072, Af);
    if (g4 != 0) Af[3] = zero8;
    #pragma unroll
    for (int kt = 0; kt < 4; ++kt)
      #pragma unroll
      for (int nt = 0; nt < 4; ++nt)
        acc[gate][nt] = __builtin_amdgcn_mfma_f32_16x16x32_bf16(Af[kt], Bf[nt][kt], acc[gate][nt], 0, 0, 0);
  }

  // ---- GRU epilogue (gathers post-MFMA; Ghh slices L2-hot) ----
  const int h0 = half * 64 + w * 16 + g4 * 4;
  f32x4 cin[3], cou[3], cz[3];
  #pragma unroll
  for (int gate = 0; gate < 3; ++gate) {
    int g = gate * 128 + h0;
    cin[gate] = *(const f32x4*)(cvec + g);
    cou[gate] = *(const f32x4*)(cvec + 384 + g);
    cz[gate]  = *(const f32x4*)(cvec + 768 + g);
  }
  #pragma unroll
  for (int nt = 0; nt < 4; ++nt) {
    int s = nt * 16 + l16;
    int node = inp[s < NS ? s : 0];
    const u16* Trow = T + (size_t)node * TW + 768 + h0;
    u16x4 gr = *(const u16x4*)(Trow);
    u16x4 gi = *(const u16x4*)(Trow + 128);
    u16x4 gn = *(const u16x4*)(Trow + 256);
    f32x4 hid = *(const f32x4*)(emb + (size_t)node * NH + h0);
    float rin = rsLds[0][s], rou = rsLds[1][s];
    f32x4 res;
    #pragma unroll
    for (int r = 0; r < 4; ++r) {
      float vr = acc[0][nt][r] + rin * cin[0][r] + rou * cou[0][r] + cz[0][r] + bf2f(gr[r]);
      float vi = acc[1][nt][r] + rin * cin[1][r] + rou * cou[1][r] + cz[1][r] + bf2f(gi[r]);
      float vn = acc[2][nt][r] + rin * cin[2][r] + rou * cou[2][r] + cz[2][r];
      float rr = sigm(vr);
      float ii = sigm(vi);
      float nn = tanh_(vn + rr * bf2f(gn[r]));
      res[r] = nn + ii * (hid[r] - nn);
    }
    if (s < NS)
      *(f32x4*)(out + ((size_t)b * NS + s) * NH + h0) = res;
  }
}

// ---------- launcher ----------
extern "C" void kernel_launch(void* const* d_in, const int* in_sizes, int n_in,
                              void* d_out, int out_size, void* d_ws, size_t ws_size,
                              hipStream_t stream) {
  const int*   inputs = (const int*)  d_in[0];
  const float* A      = (const float*)d_in[1];
  const float* emb    = (const float*)d_in[2];
  const float* W_in   = (const float*)d_in[3];
  const float* b_in   = (const float*)d_in[4];
  const float* W_out  = (const float*)d_in[5];
  const float* b_out  = (const float*)d_in[6];
  const float* w_ih   = (const float*)d_in[7];
  const float* b_ih   = (const float*)d_in[8];
  const float* w_hh   = (const float*)d_in[9];
  const float* b_hh   = (const float*)d_in[10];
  const float* b_iah  = (const float*)d_in[11];
  const float* b_oah  = (const float*)d_in[12];

  // ws layout: T (50000*1152 bf16 = 115,200,000 B) | UcatT (294,912 B) | cvec (4,608 B)
  u16*   T     = (u16*)d_ws;
  u16*   UcatT = (u16*)((char*)d_ws + 115200000);
  float* cvec  = (float*)((char*)d_ws + 115200000 + 294912);

  k1_prep<<<dim3(581), dim3(256), 0, stream>>>(W_in, b_in, W_out, b_out, w_ih, b_ih,
                                               w_hh, b_iah, b_oah, UcatT, cvec);
  k2_tables<<<dim3(782), dim3(256), 0, stream>>>(emb, UcatT, b_hh, T);
  k3_main<<<dim3(8192), dim3(256), 0, stream>>>(inputs, A, T, cvec, emb, (float*)d_out);
}

// Round 9
// 279.042 us; speedup vs baseline: 2.1953x; 1.1314x over previous
//
#include <hip/hip_runtime.h>
#include <stdint.h>

typedef unsigned short u16;
typedef unsigned int u32;
typedef unsigned long long u64;
typedef __attribute__((ext_vector_type(4))) float f32x4;
typedef __attribute__((ext_vector_type(8))) short s16x8;
typedef __attribute__((ext_vector_type(4))) u16 u16x4;
typedef __attribute__((ext_vector_type(2))) u32 u32x2;
typedef __attribute__((ext_vector_type(4))) u32 u32x4;

#define NS 50
#define NH 128
#define NNODE 50000
#define TW 1152      // table row width in u16 (Gin|Gout|Ghh)
#define GSUB 3328    // bytes per staged g-subtile: 26 tiles x 128B (rows 100..103 zero)

// ---------- helpers ----------
__device__ __forceinline__ u16 f2bf(float f) {
  u32 u = __builtin_bit_cast(u32, f);
  u32 r = (u + 0x7FFFu + ((u >> 16) & 1u)) >> 16;
  return (u16)r;
}
__device__ __forceinline__ float bf2f(u16 u) {
  return __builtin_bit_cast(float, (u32)u << 16);
}
__device__ __forceinline__ float sigm(float x) {
  return 1.0f / (1.0f + __expf(-x));
}
__device__ __forceinline__ float tanh_(float x) {
  return 1.0f - 2.0f / (1.0f + __expf(2.0f * x));
}
__device__ __forceinline__ s16x8 pack8(f32x4 a, f32x4 b) {
  s16x8 r;
  r[0] = (short)f2bf(a[0]); r[1] = (short)f2bf(a[1]);
  r[2] = (short)f2bf(a[2]); r[3] = (short)f2bf(a[3]);
  r[4] = (short)f2bf(b[0]); r[5] = (short)f2bf(b[1]);
  r[6] = (short)f2bf(b[2]); r[7] = (short)f2bf(b[3]);
  return r;
}
// truncating f32->bf16 pack via v_perm (1 op / 2 elems); A in [0,1): err <= 2^-9
__device__ __forceinline__ s16x8 pack8_trunc(f32x4 a, f32x4 b) {
  u32x4 ua = __builtin_bit_cast(u32x4, a);
  u32x4 ub = __builtin_bit_cast(u32x4, b);
  u32x4 t;
  t[0] = __builtin_amdgcn_perm(ua[1], ua[0], 0x07060302u);
  t[1] = __builtin_amdgcn_perm(ua[3], ua[2], 0x07060302u);
  t[2] = __builtin_amdgcn_perm(ub[1], ub[0], 0x07060302u);
  t[3] = __builtin_amdgcn_perm(ub[3], ub[2], 0x07060302u);
  return __builtin_bit_cast(s16x8, t);
}

// batched tr-reads: all 4 kt fragments of one gate, ONE lgkmcnt(0).
__device__ __forceinline__ void afrag_tr8(const unsigned char* p0,
                                          const unsigned char* p3,
                                          s16x8 Af[4]) {
  u32x2 r0, r1, r2, r3, r4, r5, r6, r7;
  asm volatile(
      "ds_read_b64_tr_b16 %0, %8\n\t"
      "ds_read_b64_tr_b16 %1, %8 offset:128\n\t"
      "ds_read_b64_tr_b16 %2, %8 offset:1024\n\t"
      "ds_read_b64_tr_b16 %3, %8 offset:1152\n\t"
      "ds_read_b64_tr_b16 %4, %8 offset:2048\n\t"
      "ds_read_b64_tr_b16 %5, %8 offset:2176\n\t"
      "ds_read_b64_tr_b16 %6, %9\n\t"
      "ds_read_b64_tr_b16 %7, %9 offset:128\n\t"
      "s_waitcnt lgkmcnt(0)"
      : "=&v"(r0), "=&v"(r1), "=&v"(r2), "=&v"(r3),
        "=&v"(r4), "=&v"(r5), "=&v"(r6), "=&v"(r7)
      : "v"((const __attribute__((address_space(3))) unsigned char*)p0),
        "v"((const __attribute__((address_space(3))) unsigned char*)p3)
      : "memory");
  __builtin_amdgcn_sched_barrier(0);
  u32x4 t0; t0[0] = r0[0]; t0[1] = r0[1]; t0[2] = r1[0]; t0[3] = r1[1];
  u32x4 t1; t1[0] = r2[0]; t1[1] = r2[1]; t1[2] = r3[0]; t1[3] = r3[1];
  u32x4 t2; t2[0] = r4[0]; t2[1] = r4[1]; t2[2] = r5[0]; t2[3] = r5[1];
  u32x4 t3; t3[0] = r6[0]; t3[1] = r6[1]; t3[2] = r7[0]; t3[3] = r7[1];
  Af[0] = __builtin_bit_cast(s16x8, t0);
  Af[1] = __builtin_bit_cast(s16x8, t1);
  Af[2] = __builtin_bit_cast(s16x8, t2);
  Af[3] = __builtin_bit_cast(s16x8, t3);
}

// staging bijection: idx in [0,2400) -> (t in [0,100), gs in [0,12), lo in {0,1})
__device__ __forceinline__ void stage_decomp(int idx, int& t, int& gs, int& lo) {
  int e3 = idx >> 3;
  gs = e3 / 25;
  t = ((idx >> 1) & 3) * 25 + (e3 - gs * 25);
  lo = idx & 1;
}

// GRU epilogue for one h-slice (static indexing throughout)
__device__ __forceinline__ void gru_epilogue(
    const f32x4 acc[3][4], const u16x4 gr[4], const u16x4 gi[4], const u16x4 gn[4],
    const f32x4 hid[4], const float* __restrict__ cvec,
    const float* rs0, const float* rs1,
    int habs, int l16, float* __restrict__ outB)
{
  f32x4 cin[3], cou[3], cz[3];
  #pragma unroll
  for (int gate = 0; gate < 3; ++gate) {
    int g = gate * 128 + habs;
    cin[gate] = *(const f32x4*)(cvec + g);
    cou[gate] = *(const f32x4*)(cvec + 384 + g);
    cz[gate]  = *(const f32x4*)(cvec + 768 + g);
  }
  #pragma unroll
  for (int nt = 0; nt < 4; ++nt) {
    int s = nt * 16 + l16;
    float rin = rs0[s], rou = rs1[s];
    f32x4 res;
    #pragma unroll
    for (int r = 0; r < 4; ++r) {
      float vr = acc[0][nt][r] + rin * cin[0][r] + rou * cou[0][r] + cz[0][r] + bf2f(gr[nt][r]);
      float vi = acc[1][nt][r] + rin * cin[1][r] + rou * cou[1][r] + cz[1][r] + bf2f(gi[nt][r]);
      float vn = acc[2][nt][r] + rin * cin[2][r] + rou * cou[2][r] + cz[2][r];
      float rr = sigm(vr);
      float ii = sigm(vi);
      float nn = tanh_(vn + rr * bf2f(gn[nt][r]));
      res[r] = nn + ii * (hid[nt][r] - nn);
    }
    if (s < NS)
      *(f32x4*)(outB + (size_t)s * NH + habs) = res;
  }
}

// ---------- kernel 1: fold weights -> UcatT[1152][128] bf16, cvec[3][384] f32 ----------
__global__ __launch_bounds__(256) void k1_prep(
    const float* __restrict__ W_in, const float* __restrict__ b_in,
    const float* __restrict__ W_out, const float* __restrict__ b_out,
    const float* __restrict__ w_ih, const float* __restrict__ b_ih,
    const float* __restrict__ w_hh,
    const float* __restrict__ b_iah, const float* __restrict__ b_oah,
    u16* __restrict__ UcatT, float* __restrict__ cvec)
{
  int e = blockIdx.x * 256 + threadIdx.x;
  if (e < 147456) {
    int j = e >> 7, k = e & 127;
    float s = 0.f;
    if (j < 768) {
      const float* wr = w_ih + (size_t)(j < 384 ? j : j - 384) * 256 + (j < 384 ? 0 : 128);
      const float* Wc = (j < 384 ? W_in : W_out) + k;
      #pragma unroll 8
      for (int h = 0; h < 128; ++h) s += wr[h] * Wc[h * 128];
    } else {
      s = w_hh[(size_t)(j - 768) * 128 + k];
    }
    UcatT[e] = f2bf(s);
  } else if (e < 147456 + 1152) {
    int e2 = e - 147456;
    int which = e2 / 384, g = e2 - which * 384;
    const float* wr = w_ih + (size_t)g * 256;
    float s = 0.f;
    if (which == 0) { for (int h = 0; h < 128; ++h) s += wr[h] * b_in[h]; }
    else if (which == 1) { for (int h = 0; h < 128; ++h) s += wr[128 + h] * b_out[h]; }
    else {
      for (int h = 0; h < 128; ++h) s += wr[h] * b_iah[h] + wr[128 + h] * b_oah[h];
      s += b_ih[g];
    }
    cvec[which * 384 + g] = s;
  }
}

// ---------- kernel 2: node tables T[n][1152] = emb[n] @ UcatT^T (+b_hh on Ghh part) ----------
__global__ __launch_bounds__(256, 2) void k2_tables(
    const float* __restrict__ emb, const u16* __restrict__ UcatT,
    const float* __restrict__ b_hh, u16* __restrict__ T)
{
  int tid = threadIdx.x;
  int w = tid >> 6, l = tid & 63;
  int l16 = l & 15, g4 = l >> 4;
  int n0 = blockIdx.x * 64;

  s16x8 Bf[4][4];
  #pragma unroll
  for (int nt = 0; nt < 4; ++nt) {
    int nb = n0 + nt * 16 + l16; if (nb > NNODE - 1) nb = NNODE - 1;
    const float* ep = emb + (size_t)nb * NH + g4 * 8;
    #pragma unroll
    for (int kt = 0; kt < 4; ++kt) {
      f32x4 x = *(const f32x4*)(ep + kt * 32);
      f32x4 y = *(const f32x4*)(ep + kt * 32 + 4);
      Bf[nt][kt] = pack8(x, y);
    }
  }

  for (int mt = 0; mt < 18; ++mt) {
    int j0 = w * 288 + mt * 16;
    const u16* ap = UcatT + (size_t)(j0 + l16) * 128 + g4 * 8;
    s16x8 Af[4];
    #pragma unroll
    for (int kt = 0; kt < 4; ++kt) Af[kt] = *(const s16x8*)(ap + kt * 32);

    f32x4 acc[4] = {};
    #pragma unroll
    for (int nt = 0; nt < 4; ++nt)
      #pragma unroll
      for (int kt = 0; kt < 4; ++kt)
        acc[nt] = __builtin_amdgcn_mfma_f32_16x16x32_bf16(Af[kt], Bf[nt][kt], acc[nt], 0, 0, 0);

    int jr = j0 + g4 * 4;
    f32x4 bias = {0.f, 0.f, 0.f, 0.f};
    if (jr >= 768) bias = *(const f32x4*)(b_hh + (jr - 768));
    #pragma unroll
    for (int nt = 0; nt < 4; ++nt) {
      int ns = n0 + nt * 16 + l16;
      if (ns < NNODE) {
        u32 lo = (u32)f2bf(acc[nt][0] + bias[0]) | ((u32)f2bf(acc[nt][1] + bias[1]) << 16);
        u32 hi = (u32)f2bf(acc[nt][2] + bias[2]) | ((u32)f2bf(acc[nt][3] + bias[3]) << 16);
        u32x2 v = {lo, hi};
        *(u32x2*)(T + (size_t)ns * TW + jr) = v;
      }
    }
  }
}

// ---------- kernel 3 (v7): one batch per block, both h-halves pipelined ----------
// Prologue: issue gathers for BOTH halves (shared addr calc), Bf, rowsums; write buf0.
// h0: prefetch epilogue + MFMA(buf0); write buf1 (drain free); epilogue h0.
// h1: prefetch epilogue + MFMA(buf1); epilogue h1. 2 blocks/CU, phases offset.
__global__ __launch_bounds__(256, 2) void k3_main(
    const int* __restrict__ inputs, const float* __restrict__ A,
    const u16* __restrict__ T, const float* __restrict__ cvec,
    const float* __restrict__ emb, float* __restrict__ out)
{
  __shared__ __align__(128) unsigned char Glds[24 * GSUB];  // 79872 B (buf0: 0..11, buf1: 12..23)
  __shared__ float rsLds[2][64];

  const int tid = threadIdx.x;
  const int b = blockIdx.x;
  const int w = tid >> 6, l = tid & 63;
  const int l16 = l & 15, g4 = l >> 4;

  const float* Ab = A + (size_t)b * (NS * 2 * NS);
  const int* inp = inputs + b * NS;
  const char* Tb = (const char*)T;
  float* outB = out + (size_t)b * NS * NH;

  if (tid < 128) ((float*)rsLds)[tid] = 0.f;

  // ---- vectorized f32 rowsums (threads 0..99, 13 f32x4 loads each) ----
  if (tid < 100) {
    int s = tid < 50 ? tid : tid - 50;
    const float* ap = Ab + s * 100;
    float sum;
    if (tid < 50) {
      f32x4 a4 = *(const f32x4*)ap;
      #pragma unroll
      for (int q = 1; q < 12; ++q) a4 += *(const f32x4*)(ap + q * 4);
      f32x4 vt = *(const f32x4*)(ap + 48);
      sum = (a4[0] + a4[1]) + (a4[2] + a4[3]) + vt[0] + vt[1];
    } else {
      f32x4 vt = *(const f32x4*)(ap + 48);
      f32x4 a4 = *(const f32x4*)(ap + 52);
      #pragma unroll
      for (int q = 1; q < 12; ++q) a4 += *(const f32x4*)(ap + 52 + q * 4);
      sum = (a4[0] + a4[1]) + (a4[2] + a4[3]) + vt[2] + vt[3];
    }
    rsLds[tid < 50 ? 0 : 1][s] = sum;
  }

  // ---- issue gathers for BOTH halves (shared address calc) ----
  u32x4 st0[10], st1[10];
  #pragma unroll
  for (int i = 0; i < 10; ++i) {
    int idx = i * 256 + tid;
    if (i < 9 || tid < 96) {
      int t, gs, lo; stage_decomp(idx, t, gs, lo);
      int node = inp[t < NS ? t : t - NS];
      u32 ro = (u32)node * (TW * 2) + (t < NS ? 0u : 768u);
      int gate = gs >> 2, wv = gs & 3;
      const char* p = Tb + ro + gate * 256 + wv * 32 + lo * 16;
      st0[i] = *(const u32x4*)(p);
      st1[i] = *(const u32x4*)(p + 128);
    }
  }

  // ---- B-fragments (shared by both halves) ----
  s16x8 Bf[4][4];
  #pragma unroll
  for (int nt = 0; nt < 4; ++nt) {
    int s = nt * 16 + l16; if (s > NS - 1) s = NS - 1;
    const float* ap = Ab + s * 100;
    #pragma unroll
    for (int kt = 0; kt < 4; ++kt) {
      f32x4 x = {0.f, 0.f, 0.f, 0.f}, y = {0.f, 0.f, 0.f, 0.f};
      if (kt < 3) {
        x = *(const f32x4*)(ap + kt * 32 + g4 * 8);
        y = *(const f32x4*)(ap + kt * 32 + g4 * 8 + 4);
      } else if (g4 == 0) {
        x = *(const f32x4*)(ap + 96);   // t 96..99; 100..103 zero
      }
      Bf[nt][kt] = pack8_trunc(x, y);
    }
  }

  // ---- zero pad tiles (t 100..103 of all 24 subtiles) ----
  if (tid < 192) {
    u32x4 z = {0, 0, 0, 0};
    *(u32x4*)(Glds + (tid >> 3) * GSUB + 3200 + (tid & 7) * 16) = z;
  }

  // ---- write half-0 stage (waits only st0's loads) ----
  #pragma unroll
  for (int i = 0; i < 10; ++i) {
    int idx = i * 256 + tid;
    if (i < 9 || tid < 96) {
      int t, gs, lo; stage_decomp(idx, t, gs, lo);
      *(u32x4*)(Glds + gs * GSUB + t * 32 + lo * 16) = st0[i];
    }
  }
  __syncthreads();

  const s16x8 zero8 = {0, 0, 0, 0, 0, 0, 0, 0};
  const int hw = w * 16 + g4 * 4;   // h within a 64-col half

  // ================= HALF 0 =================
  // epilogue prefetch (flies under MFMA)
  u16x4 gr0[4], gi0[4], gn0[4]; f32x4 hid0[4];
  #pragma unroll
  for (int nt = 0; nt < 4; ++nt) {
    int s = nt * 16 + l16;
    int node = inp[s < NS ? s : 0];
    const u16* Trow = T + (size_t)node * TW + 768 + hw;
    gr0[nt] = *(const u16x4*)(Trow);
    gi0[nt] = *(const u16x4*)(Trow + 128);
    gn0[nt] = *(const u16x4*)(Trow + 256);
    hid0[nt] = *(const f32x4*)(emb + (size_t)node * NH + hw);
  }
  f32x4 acc0[3][4] = {};
  __builtin_amdgcn_s_setprio(1);
  #pragma unroll
  for (int gate = 0; gate < 3; ++gate) {
    const unsigned char* gb = Glds + (gate * 4 + w) * GSUB + l16 * 8;
    s16x8 Af[4];
    afrag_tr8(gb + g4 * 256, gb + 3072, Af);
    if (g4 != 0) Af[3] = zero8;
    #pragma unroll
    for (int kt = 0; kt < 4; ++kt)
      #pragma unroll
      for (int nt = 0; nt < 4; ++nt)
        acc0[gate][nt] = __builtin_amdgcn_mfma_f32_16x16x32_bf16(Af[kt], Bf[nt][kt], acc0[gate][nt], 0, 0, 0);
  }
  __builtin_amdgcn_s_setprio(0);

  // ---- write half-1 stage into buf1 (gathers landed under prologue/MFMA) ----
  #pragma unroll
  for (int i = 0; i < 10; ++i) {
    int idx = i * 256 + tid;
    if (i < 9 || tid < 96) {
      int t, gs, lo; stage_decomp(idx, t, gs, lo);
      *(u32x4*)(Glds + (12 + gs) * GSUB + t * 32 + lo * 16) = st1[i];
    }
  }

  // ---- epilogue h0 (fills the pre-barrier slack) ----
  gru_epilogue(acc0, gr0, gi0, gn0, hid0, cvec, &rsLds[0][0], &rsLds[1][0],
               hw, l16, outB);
  __syncthreads();

  // ================= HALF 1 =================
  u16x4 gr1[4], gi1[4], gn1[4]; f32x4 hid1[4];
  #pragma unroll
  for (int nt = 0; nt < 4; ++nt) {
    int s = nt * 16 + l16;
    int node = inp[s < NS ? s : 0];
    const u16* Trow = T + (size_t)node * TW + 768 + 64 + hw;
    gr1[nt] = *(const u16x4*)(Trow);
    gi1[nt] = *(const u16x4*)(Trow + 128);
    gn1[nt] = *(const u16x4*)(Trow + 256);
    hid1[nt] = *(const f32x4*)(emb + (size_t)node * NH + 64 + hw);
  }
  f32x4 acc1[3][4] = {};
  __builtin_amdgcn_s_setprio(1);
  #pragma unroll
  for (int gate = 0; gate < 3; ++gate) {
    const unsigned char* gb = Glds + (12 + gate * 4 + w) * GSUB + l16 * 8;
    s16x8 Af[4];
    afrag_tr8(gb + g4 * 256, gb + 3072, Af);
    if (g4 != 0) Af[3] = zero8;
    #pragma unroll
    for (int kt = 0; kt < 4; ++kt)
      #pragma unroll
      for (int nt = 0; nt < 4; ++nt)
        acc1[gate][nt] = __builtin_amdgcn_mfma_f32_16x16x32_bf16(Af[kt], Bf[nt][kt], acc1[gate][nt], 0, 0, 0);
  }
  __builtin_amdgcn_s_setprio(0);

  gru_epilogue(acc1, gr1, gi1, gn1, hid1, cvec, &rsLds[0][0], &rsLds[1][0],
               64 + hw, l16, outB);
}

// ---------- launcher ----------
extern "C" void kernel_launch(void* const* d_in, const int* in_sizes, int n_in,
                              void* d_out, int out_size, void* d_ws, size_t ws_size,
                              hipStream_t stream) {
  const int*   inputs = (const int*)  d_in[0];
  const float* A      = (const float*)d_in[1];
  const float* emb    = (const float*)d_in[2];
  const float* W_in   = (const float*)d_in[3];
  const float* b_in   = (const float*)d_in[4];
  const float* W_out  = (const float*)d_in[5];
  const float* b_out  = (const float*)d_in[6];
  const float* w_ih   = (const float*)d_in[7];
  const float* b_ih   = (const float*)d_in[8];
  const float* w_hh   = (const float*)d_in[9];
  const float* b_hh   = (const float*)d_in[10];
  const float* b_iah  = (const float*)d_in[11];
  const float* b_oah  = (const float*)d_in[12];

  // ws layout: T (50000*1152 bf16 = 115,200,000 B) | UcatT (294,912 B) | cvec (4,608 B)
  u16*   T     = (u16*)d_ws;
  u16*   UcatT = (u16*)((char*)d_ws + 115200000);
  float* cvec  = (float*)((char*)d_ws + 115200000 + 294912);

  k1_prep<<<dim3(581), dim3(256), 0, stream>>>(W_in, b_in, W_out, b_out, w_ih, b_ih,
                                               w_hh, b_iah, b_oah, UcatT, cvec);
  k2_tables<<<dim3(782), dim3(256), 0, stream>>>(emb, UcatT, b_hh, T);
  k3_main<<<dim3(4096), dim3(256), 0, stream>>>(inputs, A, T, cvec, emb, (float*)d_out);
}

// Round 10
// 243.858 us; speedup vs baseline: 2.5121x; 1.1443x over previous
//
#include <hip/hip_runtime.h>
#include <stdint.h>

typedef unsigned short u16;
typedef unsigned int u32;
typedef unsigned long long u64;
typedef __attribute__((ext_vector_type(4))) float f32x4;
typedef __attribute__((ext_vector_type(8))) short s16x8;
typedef __attribute__((ext_vector_type(4))) u16 u16x4;
typedef __attribute__((ext_vector_type(2))) u32 u32x2;
typedef __attribute__((ext_vector_type(4))) u32 u32x4;

#define NS 50
#define NH 128

// k3 LDS layout (bytes):
//   hidden_tr: 8 hc x 16 t-tiles x 128B ([4t][16h] bf16 tiles)   = 16384
//   M_sh:      50 rows x 512B (256 bf16, XOR-swizzled by (s&7)<<4) = 25600
//   A2out:     50 rows x 112B (56 bf16: A cols 50..99 at t'=col-50, pad 50..55 = 0)
//   rs:        2 x 64 f32
#define HT_OFF 0
#define M_OFF  16384
#define A2_OFF 41984
#define RS_OFF 47584
#define LDS_TOTAL 48096

// ---------- helpers ----------
__device__ __forceinline__ u16 f2bf(float f) {
  u32 u = __builtin_bit_cast(u32, f);
  u32 r = (u + 0x7FFFu + ((u >> 16) & 1u)) >> 16;
  return (u16)r;
}
__device__ __forceinline__ float bf2f(u16 u) {
  return __builtin_bit_cast(float, (u32)u << 16);
}
__device__ __forceinline__ float sigm(float x) { return 1.0f / (1.0f + __expf(-x)); }
__device__ __forceinline__ float tanh_(float x) { return 1.0f - 2.0f / (1.0f + __expf(2.0f * x)); }
__device__ __forceinline__ s16x8 pack8(f32x4 a, f32x4 b) {
  s16x8 r;
  r[0] = (short)f2bf(a[0]); r[1] = (short)f2bf(a[1]);
  r[2] = (short)f2bf(a[2]); r[3] = (short)f2bf(a[3]);
  r[4] = (short)f2bf(b[0]); r[5] = (short)f2bf(b[1]);
  r[6] = (short)f2bf(b[2]); r[7] = (short)f2bf(b[3]);
  return r;
}
// two tr-reads -> one K=32 A-fragment (proven tile geometry: [4t][16h], col=(addr>>3)&15)
__device__ __forceinline__ s16x8 afrag_tr2(const unsigned char* p) {
  u32x2 a, b;
  asm volatile(
      "ds_read_b64_tr_b16 %0, %2\n\t"
      "ds_read_b64_tr_b16 %1, %2 offset:128\n\t"
      "s_waitcnt lgkmcnt(0)"
      : "=&v"(a), "=&v"(b)
      : "v"((const __attribute__((address_space(3))) unsigned char*)p)
      : "memory");
  __builtin_amdgcn_sched_barrier(0);
  u32x4 t; t[0] = a[0]; t[1] = a[1]; t[2] = b[0]; t[3] = b[1];
  return __builtin_bit_cast(s16x8, t);
}

// ---------- kernel 1: fold weights -> UcatT[1152][128] bf16, cvec[3][384] f32 ----------
__global__ __launch_bounds__(256) void k1_prep(
    const float* __restrict__ W_in, const float* __restrict__ b_in,
    const float* __restrict__ W_out, const float* __restrict__ b_out,
    const float* __restrict__ w_ih, const float* __restrict__ b_ih,
    const float* __restrict__ w_hh,
    const float* __restrict__ b_iah, const float* __restrict__ b_oah,
    u16* __restrict__ UcatT, float* __restrict__ cvec)
{
  int e = blockIdx.x * 256 + threadIdx.x;
  if (e < 147456) {
    int j = e >> 7, k = e & 127;
    float s = 0.f;
    if (j < 768) {
      const float* wr = w_ih + (size_t)(j < 384 ? j : j - 384) * 256 + (j < 384 ? 0 : 128);
      const float* Wc = (j < 384 ? W_in : W_out) + k;
      #pragma unroll 8
      for (int h = 0; h < 128; ++h) s += wr[h] * Wc[h * 128];
    } else {
      s = w_hh[(size_t)(j - 768) * 128 + k];
    }
    UcatT[e] = f2bf(s);
  } else if (e < 147456 + 1152) {
    int e2 = e - 147456;
    int which = e2 / 384, g = e2 - which * 384;
    const float* wr = w_ih + (size_t)g * 256;
    float s = 0.f;
    if (which == 0) { for (int h = 0; h < 128; ++h) s += wr[h] * b_in[h]; }
    else if (which == 1) { for (int h = 0; h < 128; ++h) s += wr[128 + h] * b_out[h]; }
    else {
      for (int h = 0; h < 128; ++h) s += wr[h] * b_iah[h] + wr[128 + h] * b_oah[h];
      s += b_ih[g];
    }
    cvec[which * 384 + g] = s;
  }
}

// ---------- kernel 3 (v8): associativity pivot — no node tables ----------
// Per block (one batch): gather 50 emb rows -> hidden_tr (LDS, bf16, tr-subtiled).
// GEMM1: M_in/M_out = A_ext @ hidden  (A from global/A2out, hidden^T via tr-reads) -> M_sh.
// GEMM2/3: gi = [M_in|M_out] @ Ucat^T, gh = hidden @ Uhh^T (U streamed from L2, each
// element once per block; ht-split keeps acc at 96 regs). Epilogue fully local.
__global__ __launch_bounds__(256, 2) void k3_main(
    const int* __restrict__ inputs, const float* __restrict__ A,
    const u16* __restrict__ UcatT, const float* __restrict__ cvec,
    const float* __restrict__ emb, const float* __restrict__ b_hh,
    float* __restrict__ out)
{
  __shared__ __align__(128) unsigned char Sb[LDS_TOTAL];

  const int tid = threadIdx.x;
  const int b = blockIdx.x;
  const int w = tid >> 6, l = tid & 63;
  const int l16 = l & 15, g4 = l >> 4;

  const float* Ab = A + (size_t)b * (NS * 2 * NS);
  const int* inp = inputs + b * NS;
  float* outB = out + (size_t)b * NS * NH;
  float* rs = (float*)(Sb + RS_OFF);

  // ---- f32 rowsums (vectorized) ----
  if (tid < 100) {
    int s = tid < 50 ? tid : tid - 50;
    const float* ap = Ab + s * 100;
    float sum;
    if (tid < 50) {
      f32x4 a4 = *(const f32x4*)ap;
      #pragma unroll
      for (int q = 1; q < 12; ++q) a4 += *(const f32x4*)(ap + q * 4);
      f32x4 vt = *(const f32x4*)(ap + 48);
      sum = (a4[0] + a4[1]) + (a4[2] + a4[3]) + vt[0] + vt[1];
    } else {
      f32x4 vt = *(const f32x4*)(ap + 48);
      f32x4 a4 = *(const f32x4*)(ap + 52);
      #pragma unroll
      for (int q = 1; q < 12; ++q) a4 += *(const f32x4*)(ap + 52 + q * 4);
      sum = (a4[0] + a4[1]) + (a4[2] + a4[3]) + vt[2] + vt[3];
    }
    rs[(tid < 50 ? 0 : 64) + s] = sum;
  }

  // ---- zero tails: hidden_tr rows t>=50 (bytes [1600,2048) per hc) ----
  if (tid < 224) {
    int hc = tid / 28, q = tid - hc * 28;
    u32x4 z = {0, 0, 0, 0};
    *(u32x4*)(Sb + HT_OFF + hc * 2048 + 1600 + q * 16) = z;
  }
  // ---- zero A2out pad cols 50..55 ----
  if (tid < 150) {
    int row = tid / 3, d = tid - row * 3;
    *(u32*)(Sb + A2_OFF + row * 112 + 100 + d * 4) = 0u;
  }

  // ---- stage hidden_tr: 50 emb rows (the ONLY scatter in the kernel) ----
  #pragma unroll
  for (int i = 0; i < 7; ++i) {
    int slot = i * 256 + tid;
    if (slot < 1600) {
      int t = slot >> 5, hch = slot & 31;
      int node = inp[t];
      f32x4 v = *(const f32x4*)(emb + (size_t)node * NH + hch * 4);
      u32 lo = (u32)f2bf(v[0]) | ((u32)f2bf(v[1]) << 16);
      u32 hi = (u32)f2bf(v[2]) | ((u32)f2bf(v[3]) << 16);
      u32x2 pv = {lo, hi};
      *(u32x2*)(Sb + HT_OFF + (hch >> 2) * 2048 + (t >> 2) * 128 + (t & 3) * 32 + (hch & 3) * 8) = pv;
    }
  }

  // ---- stage A2out (A cols 48..99 -> bf16 at t' = col-50) ----
  #pragma unroll
  for (int i = 0; i < 3; ++i) {
    int slot = i * 256 + tid;
    if (slot < 650) {
      int row = slot / 13, q = slot - row * 13;
      f32x4 v = *(const f32x4*)(Ab + row * 100 + 48 + q * 4);
      u32 lo = (u32)f2bf(v[0]) | ((u32)f2bf(v[1]) << 16);
      u32 hi = (u32)f2bf(v[2]) | ((u32)f2bf(v[3]) << 16);
      unsigned char* rp = Sb + A2_OFF + row * 112;
      if (q == 0) {
        *(u32*)(rp) = hi;                    // cols 50,51 -> t' 0,1
      } else {
        *(u32*)(rp + (q * 8 - 4)) = lo;      // t' 4q-2,4q-1
        *(u32*)(rp + (q * 8)) = hi;          // t' 4q,4q+1
      }
    }
  }

  // ---- B-frags for GEMM1-in (global A cols 0..63, zero t>=50 on kt=1) ----
  s16x8 BfIn[4][2];
  #pragma unroll
  for (int nt = 0; nt < 4; ++nt) {
    int s = nt * 16 + l16; if (s > NS - 1) s = NS - 1;
    const float* ap = Ab + s * 100;
    {
      f32x4 x = *(const f32x4*)(ap + g4 * 8);
      f32x4 y = *(const f32x4*)(ap + g4 * 8 + 4);
      BfIn[nt][0] = pack8(x, y);
    }
    {
      f32x4 x = *(const f32x4*)(ap + 32 + g4 * 8);
      f32x4 y = *(const f32x4*)(ap + 32 + g4 * 8 + 4);
      int tb = 32 + g4 * 8;
      #pragma unroll
      for (int j = 0; j < 4; ++j) {
        if (tb + j >= NS) x[j] = 0.f;
        if (tb + 4 + j >= NS) y[j] = 0.f;
      }
      BfIn[nt][1] = pack8(x, y);
    }
  }
  __syncthreads();

  const s16x8 zero8 = {0, 0, 0, 0, 0, 0, 0, 0};

  // ---- GEMM1: M[h][s] = hidden^T @ A_ext; write M_sh[s][h|128+h] ----
  #pragma unroll
  for (int ht2 = 0; ht2 < 2; ++ht2) {
    const int htile = w * 2 + ht2;
    f32x4 accM[2][4] = {};
    #pragma unroll
    for (int kt = 0; kt < 2; ++kt) {
      s16x8 Af = afrag_tr2(Sb + HT_OFF + htile * 2048 + (kt * 8 + 2 * g4) * 128 + l16 * 8);
      #pragma unroll
      for (int nt = 0; nt < 4; ++nt)
        accM[0][nt] = __builtin_amdgcn_mfma_f32_16x16x32_bf16(Af, BfIn[nt][kt], accM[0][nt], 0, 0, 0);
      #pragma unroll
      for (int nt = 0; nt < 4; ++nt) {
        int s = nt * 16 + l16; if (s > NS - 1) s = NS - 1;
        int off = kt * 64 + g4 * 16;
        s16x8 Bo = zero8;
        if (off < 112) Bo = *(const s16x8*)(Sb + A2_OFF + s * 112 + off);
        accM[1][nt] = __builtin_amdgcn_mfma_f32_16x16x32_bf16(Af, Bo, accM[1][nt], 0, 0, 0);
      }
    }
    #pragma unroll
    for (int mo = 0; mo < 2; ++mo)
      #pragma unroll
      for (int nt = 0; nt < 4; ++nt) {
        int s = nt * 16 + l16;
        if (s < NS) {
          u32 colb = (u32)((mo * 128 + htile * 16 + g4 * 4) * 2);
          u32 swz = (u32)((s & 7) << 4);
          u32 lo = (u32)f2bf(accM[mo][nt][0]) | ((u32)f2bf(accM[mo][nt][1]) << 16);
          u32 hi = (u32)f2bf(accM[mo][nt][2]) | ((u32)f2bf(accM[mo][nt][3]) << 16);
          u32x2 pv = {lo, hi};
          *(u32x2*)(Sb + M_OFF + s * 512 + (colb ^ swz)) = pv;
        }
      }
  }
  __syncthreads();

  // ---- GEMM2 (gi) + GEMM3 (gh) + epilogue, per 16-col h-slice ----
  #pragma unroll
  for (int ht = 0; ht < 2; ++ht) {
    const int hb = w * 32 + ht * 16;
    f32x4 acc2[3][4] = {};
    f32x4 acc3[3][4] = {};
    __builtin_amdgcn_s_setprio(1);
    #pragma unroll
    for (int kt = 0; kt < 8; ++kt) {
      s16x8 Bm[4];
      #pragma unroll
      for (int nt = 0; nt < 4; ++nt) {
        int s = nt * 16 + l16; if (s > NS - 1) s = NS - 1;
        Bm[nt] = *(const s16x8*)(Sb + M_OFF + s * 512 +
                                 ((u32)(kt * 64 + g4 * 16) ^ (u32)((s & 7) << 4)));
      }
      #pragma unroll
      for (int gate = 0; gate < 3; ++gate) {
        int j = (kt < 4 ? 0 : 384) + gate * 128 + hb + l16;
        s16x8 Au = *(const s16x8*)(UcatT + (size_t)j * 128 + (kt & 3) * 32 + g4 * 8);
        #pragma unroll
        for (int nt = 0; nt < 4; ++nt)
          acc2[gate][nt] = __builtin_amdgcn_mfma_f32_16x16x32_bf16(Au, Bm[nt], acc2[gate][nt], 0, 0, 0);
      }
    }
    #pragma unroll
    for (int kt = 0; kt < 4; ++kt) {
      s16x8 Bh[4];
      #pragma unroll
      for (int nt = 0; nt < 4; ++nt) {
        int s = nt * 16 + l16; if (s > NS - 1) s = NS - 1;
        int h = kt * 32 + g4 * 8;
        Bh[nt] = *(const s16x8*)(Sb + HT_OFF + (h >> 4) * 2048 + (s >> 2) * 128 +
                                 (s & 3) * 32 + (h & 15) * 2);
      }
      #pragma unroll
      for (int gate = 0; gate < 3; ++gate) {
        int j = 768 + gate * 128 + hb + l16;
        s16x8 Au = *(const s16x8*)(UcatT + (size_t)j * 128 + kt * 32 + g4 * 8);
        #pragma unroll
        for (int nt = 0; nt < 4; ++nt)
          acc3[gate][nt] = __builtin_amdgcn_mfma_f32_16x16x32_bf16(Au, Bh[nt], acc3[gate][nt], 0, 0, 0);
      }
    }
    __builtin_amdgcn_s_setprio(0);

    const int h0 = hb + g4 * 4;
    f32x4 cin[3], cou[3], cz[3], bh[3];
    #pragma unroll
    for (int gate = 0; gate < 3; ++gate) {
      int g = gate * 128 + h0;
      cin[gate] = *(const f32x4*)(cvec + g);
      cou[gate] = *(const f32x4*)(cvec + 384 + g);
      cz[gate]  = *(const f32x4*)(cvec + 768 + g);
      bh[gate]  = *(const f32x4*)(b_hh + g);
    }
    #pragma unroll
    for (int nt = 0; nt < 4; ++nt) {
      int s = nt * 16 + l16;
      int sc = s > NS - 1 ? NS - 1 : s;
      u16x4 hid4 = *(const u16x4*)(Sb + HT_OFF + (h0 >> 4) * 2048 + (sc >> 2) * 128 +
                                   (sc & 3) * 32 + (h0 & 15) * 2);
      float rin = rs[sc], rou = rs[64 + sc];
      f32x4 res;
      #pragma unroll
      for (int r = 0; r < 4; ++r) {
        float gr_ = acc3[0][nt][r] + bh[0][r];
        float gi_ = acc3[1][nt][r] + bh[1][r];
        float gn_ = acc3[2][nt][r] + bh[2][r];
        float vr = acc2[0][nt][r] + rin * cin[0][r] + rou * cou[0][r] + cz[0][r] + gr_;
        float vi = acc2[1][nt][r] + rin * cin[1][r] + rou * cou[1][r] + cz[1][r] + gi_;
        float vn = acc2[2][nt][r] + rin * cin[2][r] + rou * cou[2][r] + cz[2][r];
        float rr = sigm(vr);
        float ii = sigm(vi);
        float nn = tanh_(vn + rr * gn_);
        res[r] = nn + ii * (bf2f(hid4[r]) - nn);
      }
      if (s < NS)
        *(f32x4*)(outB + (size_t)s * NH + h0) = res;
    }
  }
}

// ---------- launcher ----------
extern "C" void kernel_launch(void* const* d_in, const int* in_sizes, int n_in,
                              void* d_out, int out_size, void* d_ws, size_t ws_size,
                              hipStream_t stream) {
  const int*   inputs = (const int*)  d_in[0];
  const float* A      = (const float*)d_in[1];
  const float* emb    = (const float*)d_in[2];
  const float* W_in   = (const float*)d_in[3];
  const float* b_in   = (const float*)d_in[4];
  const float* W_out  = (const float*)d_in[5];
  const float* b_out  = (const float*)d_in[6];
  const float* w_ih   = (const float*)d_in[7];
  const float* b_ih   = (const float*)d_in[8];
  const float* w_hh   = (const float*)d_in[9];
  const float* b_hh   = (const float*)d_in[10];
  const float* b_iah  = (const float*)d_in[11];
  const float* b_oah  = (const float*)d_in[12];

  // ws layout: UcatT (1152*128 bf16 = 294,912 B) | cvec (3*384 f32 = 4,608 B)
  u16*   UcatT = (u16*)d_ws;
  float* cvec  = (float*)((char*)d_ws + 294912);

  k1_prep<<<dim3(581), dim3(256), 0, stream>>>(W_in, b_in, W_out, b_out, w_ih, b_ih,
                                               w_hh, b_iah, b_oah, UcatT, cvec);
  k3_main<<<dim3(4096), dim3(256), 0, stream>>>(inputs, A, UcatT, cvec, emb, b_hh,
                                                (float*)d_out);
}

// Round 11
// 223.919 us; speedup vs baseline: 2.7357x; 1.0890x over previous
//
#include <hip/hip_runtime.h>
#include <stdint.h>

typedef unsigned short u16;
typedef unsigned int u32;
typedef unsigned long long u64;
typedef __attribute__((ext_vector_type(2))) float f32x2;
typedef __attribute__((ext_vector_type(4))) float f32x4;
typedef __attribute__((ext_vector_type(8))) short s16x8;
typedef __attribute__((ext_vector_type(4))) u16 u16x4;
typedef __attribute__((ext_vector_type(2))) u32 u32x2;
typedef __attribute__((ext_vector_type(4))) u32 u32x4;

#define NS 50
#define NH 128

// k3 LDS layout (bytes):
//   hidden_tr: 8 hc x 16 t-tiles x 128B ([4t][16h] bf16 tiles) = 16384
//   M_sh:      50 rows x 512B (256 bf16, XOR-swizzled by (s&7)<<4) = 25600
//   rs:        2 x 64 f32 = 512
#define HT_OFF 0
#define M_OFF  16384
#define RS_OFF 41984
#define LDS_TOTAL 42496

// ---------- helpers ----------
__device__ __forceinline__ u16 f2bf(float f) {
  u32 u = __builtin_bit_cast(u32, f);
  u32 r = (u + 0x7FFFu + ((u >> 16) & 1u)) >> 16;
  return (u16)r;
}
__device__ __forceinline__ float bf2f(u16 u) {
  return __builtin_bit_cast(float, (u32)u << 16);
}
__device__ __forceinline__ float sigm(float x) { return 1.0f / (1.0f + __expf(-x)); }
__device__ __forceinline__ float tanh_(float x) { return 1.0f - 2.0f / (1.0f + __expf(2.0f * x)); }
__device__ __forceinline__ s16x8 pack8(f32x4 a, f32x4 b) {
  s16x8 r;
  r[0] = (short)f2bf(a[0]); r[1] = (short)f2bf(a[1]);
  r[2] = (short)f2bf(a[2]); r[3] = (short)f2bf(a[3]);
  r[4] = (short)f2bf(b[0]); r[5] = (short)f2bf(b[1]);
  r[6] = (short)f2bf(b[2]); r[7] = (short)f2bf(b[3]);
  return r;
}
// two tr-reads -> one K=32 A-fragment ([4t][16h] tiles, col=(addr>>3)&15)
__device__ __forceinline__ s16x8 afrag_tr2(const unsigned char* p) {
  u32x2 a, b;
  asm volatile(
      "ds_read_b64_tr_b16 %0, %2\n\t"
      "ds_read_b64_tr_b16 %1, %2 offset:128\n\t"
      "s_waitcnt lgkmcnt(0)"
      : "=&v"(a), "=&v"(b)
      : "v"((const __attribute__((address_space(3))) unsigned char*)p)
      : "memory");
  __builtin_amdgcn_sched_barrier(0);
  u32x4 t; t[0] = a[0]; t[1] = a[1]; t[2] = b[0]; t[3] = b[1];
  return __builtin_bit_cast(s16x8, t);
}
// A-out B-fragment direct from global (8B-aligned f32x2 pairs, masked at col 99)
__device__ __forceinline__ s16x8 load_outfrag(const float* ap, int kbase) {
  f32x4 x = {0.f, 0.f, 0.f, 0.f}, y = {0.f, 0.f, 0.f, 0.f};
  const float* p = ap + 50 + kbase;
  if (kbase <= 40) {
    f32x2 a0 = *(const f32x2*)(p);
    f32x2 a1 = *(const f32x2*)(p + 2);
    f32x2 a2 = *(const f32x2*)(p + 4);
    f32x2 a3 = *(const f32x2*)(p + 6);
    x[0] = a0[0]; x[1] = a0[1]; x[2] = a1[0]; x[3] = a1[1];
    y[0] = a2[0]; y[1] = a2[1]; y[2] = a3[0]; y[3] = a3[1];
  } else if (kbase == 48) {
    f32x2 a0 = *(const f32x2*)(p);   // cols 98,99
    x[0] = a0[0]; x[1] = a0[1];
  }
  return pack8(x, y);
}

// Upack position for element U[j][k] (j: 0..767 = Uin|Uout, 768..1151 = Uhh; k: 0..127)
// chunk = 1KB fragment read by one wave: lane l -> 16B at chunk*1024 + l*16.
__device__ __forceinline__ int upack_pos(int j, int k) {
  int kt4 = k >> 5, g4 = (k >> 3) & 3, e2 = k & 7;
  int chunk;
  if (j < 768) {
    int big = j >= 384;
    int jj = j - big * 384;
    int gate = jj >> 7, jr = jj & 127;
    chunk = ((big * 3 + gate) * 8 + (jr >> 4)) * 4 + kt4;
    return chunk * 512 + ((g4 * 16 + (jr & 15)) * 8 + e2);
  } else {
    int jj = j - 768;
    int gate = jj >> 7, jr = jj & 127;
    chunk = 192 + (gate * 8 + (jr >> 4)) * 4 + kt4;
    return chunk * 512 + ((g4 * 16 + (jr & 15)) * 8 + e2);
  }
}

// ---------- kernel 1: fold weights -> Upack (fragment-ordered) + cvec[3][384] f32 ----------
__global__ __launch_bounds__(256) void k1_prep(
    const float* __restrict__ W_in, const float* __restrict__ b_in,
    const float* __restrict__ W_out, const float* __restrict__ b_out,
    const float* __restrict__ w_ih, const float* __restrict__ b_ih,
    const float* __restrict__ w_hh,
    const float* __restrict__ b_iah, const float* __restrict__ b_oah,
    u16* __restrict__ Upk, float* __restrict__ cvec)
{
  int e = blockIdx.x * 256 + threadIdx.x;
  if (e < 147456) {
    int j = e >> 7, k = e & 127;
    float s = 0.f;
    if (j < 768) {
      const float* wr = w_ih + (size_t)(j < 384 ? j : j - 384) * 256 + (j < 384 ? 0 : 128);
      const float* Wc = (j < 384 ? W_in : W_out) + k;
      #pragma unroll 8
      for (int h = 0; h < 128; ++h) s += wr[h] * Wc[h * 128];
    } else {
      s = w_hh[(size_t)(j - 768) * 128 + k];
    }
    Upk[upack_pos(j, k)] = f2bf(s);
  } else if (e < 147456 + 1152) {
    int e2 = e - 147456;
    int which = e2 / 384, g = e2 - which * 384;
    const float* wr = w_ih + (size_t)g * 256;
    float s = 0.f;
    if (which == 0) { for (int h = 0; h < 128; ++h) s += wr[h] * b_in[h]; }
    else if (which == 1) { for (int h = 0; h < 128; ++h) s += wr[128 + h] * b_out[h]; }
    else {
      for (int h = 0; h < 128; ++h) s += wr[h] * b_iah[h] + wr[128 + h] * b_oah[h];
      s += b_ih[g];
    }
    cvec[which * 384 + g] = s;
  }
}

// ---------- kernel 3 (v9): associativity + coalesced U fragments ----------
__global__ __launch_bounds__(256, 2) void k3_main(
    const int* __restrict__ inputs, const float* __restrict__ A,
    const u16* __restrict__ Upk, const float* __restrict__ cvec,
    const float* __restrict__ emb, const float* __restrict__ b_hh,
    float* __restrict__ out)
{
  __shared__ __align__(128) unsigned char Sb[LDS_TOTAL];

  const int tid = threadIdx.x;
  const int b = blockIdx.x;
  const int w = tid >> 6, l = tid & 63;
  const int l16 = l & 15, g4 = l >> 4;

  const float* Ab = A + (size_t)b * (NS * 2 * NS);
  const int* inp = inputs + b * NS;
  float* outB = out + (size_t)b * NS * NH;
  float* rs = (float*)(Sb + RS_OFF);

  // ---- f32 rowsums (vectorized) ----
  if (tid < 100) {
    int s = tid < 50 ? tid : tid - 50;
    const float* ap = Ab + s * 100;
    float sum;
    if (tid < 50) {
      f32x4 a4 = *(const f32x4*)ap;
      #pragma unroll
      for (int q = 1; q < 12; ++q) a4 += *(const f32x4*)(ap + q * 4);
      f32x4 vt = *(const f32x4*)(ap + 48);
      sum = (a4[0] + a4[1]) + (a4[2] + a4[3]) + vt[0] + vt[1];
    } else {
      f32x4 vt = *(const f32x4*)(ap + 48);
      f32x4 a4 = *(const f32x4*)(ap + 52);
      #pragma unroll
      for (int q = 1; q < 12; ++q) a4 += *(const f32x4*)(ap + 52 + q * 4);
      sum = (a4[0] + a4[1]) + (a4[2] + a4[3]) + vt[2] + vt[3];
    }
    rs[(tid < 50 ? 0 : 64) + s] = sum;
  }

  // ---- zero tails: hidden_tr rows t>=50 (bytes [1600,2048) per hc) ----
  if (tid < 224) {
    int hc = tid / 28, q = tid - hc * 28;
    u32x4 z = {0, 0, 0, 0};
    *(u32x4*)(Sb + HT_OFF + hc * 2048 + 1600 + q * 16) = z;
  }

  // ---- stage hidden_tr: 50 emb rows (the ONLY scatter in the kernel) ----
  #pragma unroll
  for (int i = 0; i < 7; ++i) {
    int slot = i * 256 + tid;
    if (slot < 1600) {
      int t = slot >> 5, hch = slot & 31;
      int node = inp[t];
      f32x4 v = *(const f32x4*)(emb + (size_t)node * NH + hch * 4);
      u32 lo = (u32)f2bf(v[0]) | ((u32)f2bf(v[1]) << 16);
      u32 hi = (u32)f2bf(v[2]) | ((u32)f2bf(v[3]) << 16);
      u32x2 pv = {lo, hi};
      *(u32x2*)(Sb + HT_OFF + (hch >> 2) * 2048 + (t >> 2) * 128 + (t & 3) * 32 + (hch & 3) * 8) = pv;
    }
  }

  // ---- B-frags for GEMM1-in (global A cols 0..63, zero t>=50 on kt=1) ----
  s16x8 BfIn[4][2];
  #pragma unroll
  for (int nt = 0; nt < 4; ++nt) {
    int s = nt * 16 + l16; if (s > NS - 1) s = NS - 1;
    const float* ap = Ab + s * 100;
    {
      f32x4 x = *(const f32x4*)(ap + g4 * 8);
      f32x4 y = *(const f32x4*)(ap + g4 * 8 + 4);
      BfIn[nt][0] = pack8(x, y);
    }
    {
      f32x4 x = *(const f32x4*)(ap + 32 + g4 * 8);
      f32x4 y = *(const f32x4*)(ap + 32 + g4 * 8 + 4);
      int tb = 32 + g4 * 8;
      #pragma unroll
      for (int j = 0; j < 4; ++j) {
        if (tb + j >= NS) x[j] = 0.f;
        if (tb + 4 + j >= NS) y[j] = 0.f;
      }
      BfIn[nt][1] = pack8(x, y);
    }
  }
  __syncthreads();

  // ---- GEMM1: M[h][s] = hidden^T @ A_ext; write M_sh[s][h|128+h] ----
  #pragma unroll
  for (int ht2 = 0; ht2 < 2; ++ht2) {
    const int htile = w * 2 + ht2;
    f32x4 accM[2][4] = {};
    #pragma unroll
    for (int kt = 0; kt < 2; ++kt) {
      s16x8 Af = afrag_tr2(Sb + HT_OFF + htile * 2048 + (kt * 8 + 2 * g4) * 128 + l16 * 8);
      #pragma unroll
      for (int nt = 0; nt < 4; ++nt)
        accM[0][nt] = __builtin_amdgcn_mfma_f32_16x16x32_bf16(Af, BfIn[nt][kt], accM[0][nt], 0, 0, 0);
      #pragma unroll
      for (int nt = 0; nt < 4; ++nt) {
        int s = nt * 16 + l16; if (s > NS - 1) s = NS - 1;
        s16x8 Bo = load_outfrag(Ab + s * 100, kt * 32 + g4 * 8);
        accM[1][nt] = __builtin_amdgcn_mfma_f32_16x16x32_bf16(Af, Bo, accM[1][nt], 0, 0, 0);
      }
    }
    #pragma unroll
    for (int mo = 0; mo < 2; ++mo)
      #pragma unroll
      for (int nt = 0; nt < 4; ++nt) {
        int s = nt * 16 + l16;
        if (s < NS) {
          u32 colb = (u32)((mo * 128 + htile * 16 + g4 * 4) * 2);
          u32 swz = (u32)((s & 7) << 4);
          u32 lo = (u32)f2bf(accM[mo][nt][0]) | ((u32)f2bf(accM[mo][nt][1]) << 16);
          u32 hi = (u32)f2bf(accM[mo][nt][2]) | ((u32)f2bf(accM[mo][nt][3]) << 16);
          u32x2 pv = {lo, hi};
          *(u32x2*)(Sb + M_OFF + s * 512 + (colb ^ swz)) = pv;
        }
      }
  }
  __syncthreads();

  // ---- GEMM2 (gi) + GEMM3 (gh) + epilogue, per 16-col h-slice ----
  const u16* upLane = Upk + (size_t)l * 8;   // lane's 16B slot within each 1KB chunk
  #pragma unroll
  for (int ht = 0; ht < 2; ++ht) {
    const int hb = w * 32 + ht * 16;
    const int js = w * 2 + ht;
    f32x4 acc2[3][4] = {};
    f32x4 acc3[3][4] = {};
    __builtin_amdgcn_s_setprio(1);
    #pragma unroll
    for (int kt = 0; kt < 8; ++kt) {
      s16x8 Bm[4];
      #pragma unroll
      for (int nt = 0; nt < 4; ++nt) {
        int s = nt * 16 + l16; if (s > NS - 1) s = NS - 1;
        Bm[nt] = *(const s16x8*)(Sb + M_OFF + s * 512 +
                                 ((u32)(kt * 64 + g4 * 16) ^ (u32)((s & 7) << 4)));
      }
      const int big = kt >> 2, kt4 = kt & 3;
      #pragma unroll
      for (int gate = 0; gate < 3; ++gate) {
        int chunk = ((big * 3 + gate) * 8 + js) * 4 + kt4;
        s16x8 Au = *(const s16x8*)(upLane + chunk * 512);
        #pragma unroll
        for (int nt = 0; nt < 4; ++nt)
          acc2[gate][nt] = __builtin_amdgcn_mfma_f32_16x16x32_bf16(Au, Bm[nt], acc2[gate][nt], 0, 0, 0);
      }
    }
    #pragma unroll
    for (int kt = 0; kt < 4; ++kt) {
      s16x8 Bh[4];
      #pragma unroll
      for (int nt = 0; nt < 4; ++nt) {
        int s = nt * 16 + l16; if (s > NS - 1) s = NS - 1;
        int h = kt * 32 + g4 * 8;
        Bh[nt] = *(const s16x8*)(Sb + HT_OFF + (h >> 4) * 2048 + (s >> 2) * 128 +
                                 (s & 3) * 32 + (h & 15) * 2);
      }
      #pragma unroll
      for (int gate = 0; gate < 3; ++gate) {
        int chunk = 192 + (gate * 8 + js) * 4 + kt;
        s16x8 Au = *(const s16x8*)(upLane + chunk * 512);
        #pragma unroll
        for (int nt = 0; nt < 4; ++nt)
          acc3[gate][nt] = __builtin_amdgcn_mfma_f32_16x16x32_bf16(Au, Bh[nt], acc3[gate][nt], 0, 0, 0);
      }
    }
    __builtin_amdgcn_s_setprio(0);

    const int h0 = hb + g4 * 4;
    f32x4 cin[3], cou[3], cz[3], bh[3];
    #pragma unroll
    for (int gate = 0; gate < 3; ++gate) {
      int g = gate * 128 + h0;
      cin[gate] = *(const f32x4*)(cvec + g);
      cou[gate] = *(const f32x4*)(cvec + 384 + g);
      cz[gate]  = *(const f32x4*)(cvec + 768 + g);
      bh[gate]  = *(const f32x4*)(b_hh + g);
    }
    #pragma unroll
    for (int nt = 0; nt < 4; ++nt) {
      int s = nt * 16 + l16;
      int sc = s > NS - 1 ? NS - 1 : s;
      u16x4 hid4 = *(const u16x4*)(Sb + HT_OFF + (h0 >> 4) * 2048 + (sc >> 2) * 128 +
                                   (sc & 3) * 32 + (h0 & 15) * 2);
      float rin = rs[sc], rou = rs[64 + sc];
      f32x4 res;
      #pragma unroll
      for (int r = 0; r < 4; ++r) {
        float gr_ = acc3[0][nt][r] + bh[0][r];
        float gi_ = acc3[1][nt][r] + bh[1][r];
        float gn_ = acc3[2][nt][r] + bh[2][r];
        float vr = acc2[0][nt][r] + rin * cin[0][r] + rou * cou[0][r] + cz[0][r] + gr_;
        float vi = acc2[1][nt][r] + rin * cin[1][r] + rou * cou[1][r] + cz[1][r] + gi_;
        float vn = acc2[2][nt][r] + rin * cin[2][r] + rou * cou[2][r] + cz[2][r];
        float rr = sigm(vr);
        float ii = sigm(vi);
        float nn = tanh_(vn + rr * gn_);
        res[r] = nn + ii * (bf2f(hid4[r]) - nn);
      }
      if (s < NS)
        *(f32x4*)(outB + (size_t)s * NH + h0) = res;
    }
  }
}

// ---------- launcher ----------
extern "C" void kernel_launch(void* const* d_in, const int* in_sizes, int n_in,
                              void* d_out, int out_size, void* d_ws, size_t ws_size,
                              hipStream_t stream) {
  const int*   inputs = (const int*)  d_in[0];
  const float* A      = (const float*)d_in[1];
  const float* emb    = (const float*)d_in[2];
  const float* W_in   = (const float*)d_in[3];
  const float* b_in   = (const float*)d_in[4];
  const float* W_out  = (const float*)d_in[5];
  const float* b_out  = (const float*)d_in[6];
  const float* w_ih   = (const float*)d_in[7];
  const float* b_ih   = (const float*)d_in[8];
  const float* w_hh   = (const float*)d_in[9];
  const float* b_hh   = (const float*)d_in[10];
  const float* b_iah  = (const float*)d_in[11];
  const float* b_oah  = (const float*)d_in[12];

  // ws layout: Upk (1152*128 bf16 = 294,912 B, fragment-ordered) | cvec (4,608 B)
  u16*   Upk  = (u16*)d_ws;
  float* cvec = (float*)((char*)d_ws + 294912);

  k1_prep<<<dim3(581), dim3(256), 0, stream>>>(W_in, b_in, W_out, b_out, w_ih, b_ih,
                                               w_hh, b_iah, b_oah, Upk, cvec);
  k3_main<<<dim3(4096), dim3(256), 0, stream>>>(inputs, A, Upk, cvec, emb, b_hh,
                                                (float*)d_out);
}